// Round 13
// baseline (133.531 us; speedup 1.0000x reference)
//
#include <hip/hip_runtime.h>
#include <hip/hip_bf16.h>

constexpr int B_ = 32, C_ = 256, H_ = 32, W_ = 32, M_ = 1024;
constexpr int NH = 4, DK = 16, DV = 64;
constexpr float EPS = 1e-5f;

using bf16x8 = __bf16 __attribute__((ext_vector_type(8)));
using f32x4  = float __attribute__((ext_vector_type(4)));

struct alignas(8) Bf4 { __bf16 a, b, c, d; };

// ---------------- Kernel 0: W fp32 -> bf16 (once; 36864 elems) -------------
__global__ __launch_bounds__(256) void k_wbf(
    const float* __restrict__ w, __bf16* __restrict__ wbf)
{
    int i = blockIdx.x * 256 + threadIdx.x;          // 9216 float4s
    if (i < 9216) {
        float4 f = reinterpret_cast<const float4*>(w)[i];
        Bf4 o{(__bf16)f.x, (__bf16)f.y, (__bf16)f.z, (__bf16)f.w};
        *reinterpret_cast<Bf4*>(&wbf[i * 4]) = o;
    }
}

// ---------------- Kernel 1: qkv = W @ x via bf16 MFMA, + BN ----------------
// (round-11 version, proven)
__global__ __launch_bounds__(256) void k_qkv(
    const float* __restrict__ x, const __bf16* __restrict__ wbf,
    const float* __restrict__ qg, const float* __restrict__ qb,
    const float* __restrict__ qm, const float* __restrict__ qv,
    const float* __restrict__ vg, const float* __restrict__ vb,
    const float* __restrict__ vm, const float* __restrict__ vv,
    float* __restrict__ q_out, float* __restrict__ k_out,
    float* __restrict__ v_out)
{
    __shared__ __bf16 xT[64 * 72];                 // 9 KB
    __shared__ __align__(16) float ostage[64 * 68]; // 17 KB (reused per pass)
    __shared__ __align__(16) float inv_s[144];
    __shared__ __align__(16) float add_s[144];

    const int b    = blockIdx.x >> 4;
    const int m0   = (blockIdx.x & 15) * 64;
    const int tid  = threadIdx.x;
    const int wv   = tid >> 6;
    const int lane = tid & 63;
    const int col  = lane & 15;
    const int rowg = lane >> 4;

    if (tid < 144) {
        float iv = 1.f, ad = 0.f;
        if (tid < 64)       { iv = qg[tid] * rsqrtf(qv[tid] + EPS); ad = qb[tid] - qm[tid] * iv; }
        else if (tid >= 80) { int d = tid - 80; iv = vg[d] * rsqrtf(vv[d] + EPS); ad = vb[d] - vm[d] * iv; }
        inv_s[tid] = iv; add_s[tid] = ad;
    }

    f32x4 acc[9];
#pragma unroll
    for (int j = 0; j < 9; j++) acc[j] = (f32x4){0.f, 0.f, 0.f, 0.f};

    for (int c0 = 0; c0 < C_; c0 += 64) {
        __syncthreads();
#pragma unroll
        for (int i = 0; i < 4; i++) {
            int flat = tid + 256 * i;
            int m = flat & 63, c4 = flat >> 6;
            const float* xp = &x[((size_t)b * C_ + c0 + c4 * 4) * M_ + m0 + m];
            float f0 = xp[0], f1 = xp[M_], f2 = xp[2 * M_], f3 = xp[3 * M_];
            Bf4 o{(__bf16)f0, (__bf16)f1, (__bf16)f2, (__bf16)f3};
            *reinterpret_cast<Bf4*>(&xT[m * 72 + c4 * 4]) = o;
        }
        __syncthreads();
#pragma unroll
        for (int ks = 0; ks < 2; ks++) {
            const int cl = ks * 32 + rowg * 8;
            bf16x8 bf = *reinterpret_cast<const bf16x8*>(
                &xT[(16 * wv + col) * 72 + cl]);
#pragma unroll
            for (int j = 0; j < 9; j++) {
                bf16x8 af = *reinterpret_cast<const bf16x8*>(
                    &wbf[(size_t)(16 * j + col) * C_ + c0 + cl]);
                acc[j] = __builtin_amdgcn_mfma_f32_16x16x32_bf16(af, bf, acc[j], 0, 0, 0);
            }
        }
    }

    const int mloc = 16 * wv + col;

    __syncthreads();
#pragma unroll
    for (int j = 0; j < 4; j++)
        *reinterpret_cast<f32x4*>(&ostage[mloc * 68 + 16 * j + rowg * 4]) = acc[j];
    __syncthreads();
#pragma unroll
    for (int i = 0; i < 4; i++) {
        int fl = tid + 256 * i;
        int m = fl >> 4, oc4 = (fl & 15) * 4;
        float4 vr = *reinterpret_cast<const float4*>(&ostage[m * 68 + oc4]);
        float4 iv = *reinterpret_cast<const float4*>(&inv_s[oc4]);
        float4 ad = *reinterpret_cast<const float4*>(&add_s[oc4]);
        float4 rs{vr.x * iv.x + ad.x, vr.y * iv.y + ad.y,
                  vr.z * iv.z + ad.z, vr.w * iv.w + ad.w};
        *reinterpret_cast<float4*>(&q_out[((size_t)b * M_ + m0 + m) * 64 + oc4]) = rs;
    }

    __syncthreads();
#pragma unroll
    for (int r = 0; r < 4; r++)
        ostage[(rowg * 4 + r) * 68 + mloc] = acc[4][r];
    __syncthreads();
    {
        int kk = tid >> 4, m4 = (tid & 15) * 4;
        float4 vr = *reinterpret_cast<const float4*>(&ostage[kk * 68 + m4]);
        *reinterpret_cast<float4*>(&k_out[((size_t)b * DK + kk) * M_ + m0 + m4]) = vr;
    }

    __syncthreads();
#pragma unroll
    for (int j = 5; j < 9; j++)
        *reinterpret_cast<f32x4*>(&ostage[mloc * 68 + 16 * (j - 5) + rowg * 4]) = acc[j];
    __syncthreads();
#pragma unroll
    for (int i = 0; i < 4; i++) {
        int fl = tid + 256 * i;
        int m = fl >> 4, oc4 = (fl & 15) * 4;
        float4 vr = *reinterpret_cast<const float4*>(&ostage[m * 68 + oc4]);
        float4 iv = *reinterpret_cast<const float4*>(&inv_s[80 + oc4]);
        float4 ad = *reinterpret_cast<const float4*>(&add_s[80 + oc4]);
        float4 rs{vr.x * iv.x + ad.x, vr.y * iv.y + ad.y,
                  vr.z * iv.z + ad.z, vr.w * iv.w + ad.w};
        *reinterpret_cast<float4*>(&v_out[((size_t)b * M_ + m0 + m) * 64 + oc4]) = rs;
    }
}

// ---------------- Kernel 2: softmax over M per (b,k) row, in place ---------
__global__ __launch_bounds__(256) void k_softmax(float* __restrict__ kl)
{
    float* p = kl + (size_t)blockIdx.x * M_;
    const int tid = threadIdx.x;
    float v[4];
    float mx = -1e30f;
#pragma unroll
    for (int i = 0; i < 4; i++) { v[i] = p[tid + 256 * i]; mx = fmaxf(mx, v[i]); }
#pragma unroll
    for (int off = 32; off >= 1; off >>= 1) mx = fmaxf(mx, __shfl_xor(mx, off));
    __shared__ float red[8];
    if ((tid & 63) == 0) red[tid >> 6] = mx;
    __syncthreads();
    mx = fmaxf(fmaxf(red[0], red[1]), fmaxf(red[2], red[3]));
    float s = 0.f;
#pragma unroll
    for (int i = 0; i < 4; i++) { v[i] = __expf(v[i] - mx); s += v[i]; }
#pragma unroll
    for (int off = 32; off >= 1; off >>= 1) s += __shfl_xor(s, off);
    if ((tid & 63) == 0) red[4 + (tid >> 6)] = s;
    __syncthreads();
    s = red[4] + red[5] + red[6] + red[7];
    float inv = 1.f / s;
#pragma unroll
    for (int i = 0; i < 4; i++) p[tid + 256 * i] = v[i] * inv;
}

// ---------------- Kernel 3: content_lam[b,k,vd] = sum_m ksm * v ------------
__global__ __launch_bounds__(256) void k_clam(
    const float* __restrict__ ksm, const float* __restrict__ vbn,
    float* __restrict__ clam)
{
    const int b   = blockIdx.x >> 3;
    const int m0  = (blockIdx.x & 7) * 128;
    const int tid = threadIdx.x;
    const int vd  = tid & 63;
    const int kq  = tid >> 6;
    float acc[4] = {0.f, 0.f, 0.f, 0.f};
    for (int mi = 0; mi < 128; mi++) {
        const int m = m0 + mi;
        const float vvv = vbn[(b * M_ + m) * DV + vd];
#pragma unroll
        for (int j = 0; j < 4; j++)
            acc[j] = fmaf(ksm[(b * DK + kq + 4 * j) * M_ + m], vvv, acc[j]);
    }
#pragma unroll
    for (int j = 0; j < 4; j++)
        atomicAdd(&clam[(b * DK + kq + 4 * j) * DV + vd], acc[j]);
}

// ---------------- Kernel 3.5: s[b][m][52tap][4n] = q . lw^T ----------------
// s[n,m,tap] = sum_k qBN[b,m,n,k] * lw[k,tap].  grid 32b x 16 (64-m tiles),
// 256 thr = 4 waves; lane t = tap (t<52, taps 49..51 zero via padded lw LDS);
// wave w handles m = m0 + 16w + i.  q loads wave-uniform (scalarizable);
// writes: lane t -> 16B at t*16 -> coalesced 832B/wave.
__global__ __launch_bounds__(256) void k_sq(
    const float* __restrict__ qbn, const float* __restrict__ lw,
    float* __restrict__ s)
{
    __shared__ float lws[16 * 52];
    const int b   = blockIdx.x >> 4;
    const int m0  = (blockIdx.x & 15) * 64;
    const int tid = threadIdx.x;
    for (int i = tid; i < 832; i += 256) {
        int k = i / 52, t = i % 52;
        lws[i] = (t < 49) ? lw[k * 49 + t] : 0.f;
    }
    __syncthreads();
    const int w = tid >> 6, t = tid & 63;
    if (t < 52) {
        float lwr[16];
#pragma unroll
        for (int k = 0; k < 16; k++) lwr[k] = lws[k * 52 + t];
#pragma unroll 1
        for (int i = 0; i < 16; i++) {
            const int m = m0 + w * 16 + i;
            const float* qp = qbn + ((size_t)b * M_ + m) * 64;
            float4 acc = make_float4(0.f, 0.f, 0.f, 0.f);
#pragma unroll
            for (int k = 0; k < 16; k++) {
                acc.x = fmaf(qp[k],      lwr[k], acc.x);
                acc.y = fmaf(qp[16 + k], lwr[k], acc.y);
                acc.z = fmaf(qp[32 + k], lwr[k], acc.z);
                acc.w = fmaf(qp[48 + k], lwr[k], acc.w);
            }
            *reinterpret_cast<float4*>(&s[(((size_t)b * M_ + m) * 52 + t) * 4]) = acc;
        }
    }
}

// ---------------- Kernel 4 (NEW): out = q.(clam+lb) + sum_tap s*v ----------
// grid 32b x 8 (4-row tiles), 512 thr: vd=lane, pg=wave (4 px).
// v halo 80KB LDS (proven); per-grp s chunk (32px x 52tap x 4n fp32, 26.6KB)
// staged contiguous from global; ostage[64][132] per-row flush (r7 shape).
// Inner: po[4ip][4n] (16 acc) += vr * s4 (broadcast b128) -- 196 FMA/px vs
// old conv's 784.  LDS total ~146 KB.
__global__ __launch_bounds__(512) void k_fuse(
    const float* __restrict__ vbn, const float* __restrict__ qbn,
    const float* __restrict__ clam, const float* __restrict__ s,
    const float* __restrict__ lb, float* __restrict__ out)
{
    __shared__ float v_s[10 * 32 * 64];    // 80 KB
    __shared__ float s_s[32 * 52 * 4];     // 26.6 KB
    __shared__ float ostage[64][132];      // 33.8 KB
    __shared__ float cl_s[16 * 64];
    __shared__ float lb_s[16];

    const int b   = blockIdx.x >> 3;
    const int rt  = blockIdx.x & 7;
    const int h0  = rt * 4;
    const int tid = threadIdx.x;

    for (int i4 = tid; i4 < 5120; i4 += 512) {   // v halo
        int r   = i4 >> 9;
        int rem = (i4 & 511) * 4;
        int gr  = h0 - 3 + r;
        float4 val = make_float4(0.f, 0.f, 0.f, 0.f);
        if (gr >= 0 && gr < H_)
            val = *reinterpret_cast<const float4*>(&vbn[(b * M_ + gr * W_) * DV + rem]);
        *reinterpret_cast<float4*>(&v_s[r * 2048 + rem]) = val;
    }
    if (tid < 256)
        *reinterpret_cast<float4*>(&cl_s[tid * 4]) =
            *reinterpret_cast<const float4*>(&clam[b * DK * DV + tid * 4]);
    if (tid < 16) lb_s[tid] = lb[tid];

    const int vd  = tid & 63;
    const int pg  = tid >> 6;
    const int px0 = pg * 4;

    for (int grp = 0; grp < 4; grp++) {
        // stage this row's s chunk: 32px * 208 floats = 1664 float4
        const float* sg = s + ((size_t)b * M_ + (h0 + grp) * W_) * 208;
        for (int i4 = tid; i4 < 1664; i4 += 512)
            reinterpret_cast<float4*>(s_s)[i4] =
                reinterpret_cast<const float4*>(sg)[i4];
        __syncthreads();                    // s_s (and first-iter v_s/cl/lb) ready

        float po[4][4];
#pragma unroll
        for (int ip = 0; ip < 4; ip++)
#pragma unroll
            for (int n = 0; n < 4; n++) po[ip][n] = 0.f;

#pragma unroll 1
        for (int dy = 0; dy < 7; dy++) {
            const int rbase = (grp + dy) * W_;
            float vr[10];
#pragma unroll
            for (int j = 0; j < 10; j++) {
                const int colc = px0 - 3 + j;
                vr[j] = (colc >= 0 && colc < W_) ? v_s[(rbase + colc) * DV + vd] : 0.f;
            }
#pragma unroll
            for (int dx = 0; dx < 7; dx++) {
                const int tap = dy * 7 + dx;
#pragma unroll
                for (int ip = 0; ip < 4; ip++) {
                    float4 s4 = *reinterpret_cast<const float4*>(
                        &s_s[(px0 + ip) * 208 + tap * 4]);
                    const float vv = vr[ip + dx];
                    po[ip][0] = fmaf(vv, s4.x, po[ip][0]);
                    po[ip][1] = fmaf(vv, s4.y, po[ip][1]);
                    po[ip][2] = fmaf(vv, s4.z, po[ip][2]);
                    po[ip][3] = fmaf(vv, s4.w, po[ip][3]);
                }
            }
        }
        // epilogue: content matmul + po, 4 px -> ostage[vd][p*4..]
        const int mrow = (h0 + grp) * W_;
#pragma unroll
        for (int ip = 0; ip < 4; ip++) {
            const int p = px0 + ip;              // 0..31 within row
            const int m = mrow + p;
            float lamv[16];
#pragma unroll
            for (int k = 0; k < 16; k++)
                lamv[k] = cl_s[k * DV + vd] + lb_s[k];
            const float* qp = qbn + (size_t)(b * M_ + m) * NH * DK;
            float4 ov;
            float* ovp = reinterpret_cast<float*>(&ov);
#pragma unroll
            for (int n = 0; n < 4; n++) {
                const float4* q4 = reinterpret_cast<const float4*>(qp + n * DK);
                float4 qa = q4[0], qb4 = q4[1], qc = q4[2], qd = q4[3];
                ovp[n] = po[ip][n]
                       + qa.x * lamv[0] + qa.y * lamv[1] + qa.z * lamv[2] + qa.w * lamv[3]
                       + qb4.x * lamv[4] + qb4.y * lamv[5] + qb4.z * lamv[6] + qb4.w * lamv[7]
                       + qc.x * lamv[8] + qc.y * lamv[9] + qc.z * lamv[10] + qc.w * lamv[11]
                       + qd.x * lamv[12] + qd.y * lamv[13] + qd.z * lamv[14] + qd.w * lamv[15];
            }
            *reinterpret_cast<float4*>(&ostage[vd][p * 4]) = ov;
        }
        __syncthreads();
        // flush this row: 2048 float4, coalesced
        {
            const int mrow4 = mrow * 4;
            for (int i4 = tid; i4 < 2048; i4 += 512) {
                const int vdw  = i4 >> 5;
                const int off4 = (i4 & 31) * 4;
                float4 val = *reinterpret_cast<const float4*>(&ostage[vdw][off4]);
                *reinterpret_cast<float4*>(
                    out + (size_t)b * (C_ * M_) + (size_t)vdw * 4096 + mrow4 + off4) = val;
            }
        }
        __syncthreads();
    }
}

// ---------------- Fallback kernel 4 (round-12 proven, 65 us) ---------------
__global__ __launch_bounds__(512) void k_fuse_v(
    const float* __restrict__ vbn, const float* __restrict__ qbn,
    const float* __restrict__ clam,
    const float* __restrict__ lw, const float* __restrict__ lb,
    float* __restrict__ out)
{
    __shared__ float v_s[10 * 32 * 64];
    __shared__ float ostage[64][260];
    __shared__ float lw_t[49 * 16];
    __shared__ float cl_s[16 * 64];
    __shared__ float lb_s[16];

    const int b   = blockIdx.x >> 3;
    const int rt  = blockIdx.x & 7;
    const int h0  = rt * 4;
    const int tid = threadIdx.x;

    for (int i4 = tid; i4 < 5120; i4 += 512) {
        int r   = i4 >> 9;
        int rem = (i4 & 511) * 4;
        int gr  = h0 - 3 + r;
        float4 val = make_float4(0.f, 0.f, 0.f, 0.f);
        if (gr >= 0 && gr < H_)
            val = *reinterpret_cast<const float4*>(&vbn[(b * M_ + gr * W_) * DV + rem]);
        *reinterpret_cast<float4*>(&v_s[r * 2048 + rem]) = val;
    }
    for (int i = tid; i < 784; i += 512) {
        int tap = i >> 4, k = i & 15;
        lw_t[i] = lw[k * 49 + tap];
    }
    if (tid < 256)
        *reinterpret_cast<float4*>(&cl_s[tid * 4]) =
            *reinterpret_cast<const float4*>(&clam[b * DK * DV + tid * 4]);
    if (tid < 16) lb_s[tid] = lb[tid];
    __syncthreads();

    const int vd  = tid & 63;
    const int pg  = tid >> 6;
    const int px0 = pg * 4;

    for (int grp = 0; grp < 4; grp++) {
        float plam[4][16];
#pragma unroll
        for (int ip = 0; ip < 4; ip++)
#pragma unroll
            for (int k = 0; k < 16; k++) plam[ip][k] = 0.f;

#pragma unroll 1
        for (int dy = 0; dy < 7; dy++) {
            const int rbase = (grp + dy) * W_;
            float vr[10];
#pragma unroll
            for (int j = 0; j < 10; j++) {
                const int col = px0 - 3 + j;
                vr[j] = (col >= 0 && col < W_) ? v_s[(rbase + col) * DV + vd] : 0.f;
            }
#pragma unroll
            for (int dx = 0; dx < 7; dx++) {
                const float* lwp = &lw_t[(dy * 7 + dx) * 16];
                float4 l0 = *reinterpret_cast<const float4*>(lwp);
                float4 l1 = *reinterpret_cast<const float4*>(lwp + 4);
                float4 l2 = *reinterpret_cast<const float4*>(lwp + 8);
                float4 l3 = *reinterpret_cast<const float4*>(lwp + 12);
                const float lwv[16] = {l0.x, l0.y, l0.z, l0.w, l1.x, l1.y, l1.z, l1.w,
                                       l2.x, l2.y, l2.z, l2.w, l3.x, l3.y, l3.z, l3.w};
#pragma unroll
                for (int ip = 0; ip < 4; ip++) {
                    const float vvv = vr[ip + dx];
#pragma unroll
                    for (int k = 0; k < 16; k++)
                        plam[ip][k] = fmaf(vvv, lwv[k], plam[ip][k]);
                }
            }
        }
#pragma unroll
        for (int ip = 0; ip < 4; ip++) {
            const int p = grp * 32 + px0 + ip;
            const int m = h0 * W_ + p;
            float lamv[16];
#pragma unroll
            for (int k = 0; k < 16; k++)
                lamv[k] = plam[ip][k] + cl_s[k * DV + vd] + lb_s[k];
            const float* qp = qbn + (size_t)(b * M_ + m) * NH * DK;
            float4 ov;
            float* ovp = reinterpret_cast<float*>(&ov);
#pragma unroll
            for (int n = 0; n < 4; n++) {
                const float4* q4 = reinterpret_cast<const float4*>(qp + n * DK);
                float4 qa = q4[0], qb4 = q4[1], qc = q4[2], qd = q4[3];
                ovp[n] = qa.x * lamv[0] + qa.y * lamv[1] + qa.z * lamv[2] + qa.w * lamv[3]
                       + qb4.x * lamv[4] + qb4.y * lamv[5] + qb4.z * lamv[6] + qb4.w * lamv[7]
                       + qc.x * lamv[8] + qc.y * lamv[9] + qc.z * lamv[10] + qc.w * lamv[11]
                       + qd.x * lamv[12] + qd.y * lamv[13] + qd.z * lamv[14] + qd.w * lamv[15];
            }
            *reinterpret_cast<float4*>(&ostage[vd][(p & 63) * 4]) = ov;
        }
        if (grp & 1) {
            __syncthreads();
            const int half = grp >> 1;
            const int mb4 = (h0 + half * 2) * W_ * 4;
            for (int i = tid; i < 4096; i += 512) {
                const int vdw  = i >> 6;
                const int off4 = (i & 63) * 4;
                float4 val = *reinterpret_cast<const float4*>(&ostage[vdw][off4]);
                *reinterpret_cast<float4*>(
                    out + (size_t)b * (C_ * M_) + (size_t)vdw * 4096 + mb4 + off4) = val;
            }
            __syncthreads();
        }
    }
}

extern "C" void kernel_launch(void* const* d_in, const int* in_sizes, int n_in,
                              void* d_out, int out_size, void* d_ws, size_t ws_size,
                              hipStream_t stream)
{
    (void)in_sizes; (void)n_in; (void)out_size;
    const float* x   = (const float*)d_in[0];
    const float* w   = (const float*)d_in[1];
    const float* qg  = (const float*)d_in[2];
    const float* qb  = (const float*)d_in[3];
    const float* qm  = (const float*)d_in[4];
    const float* qvr = (const float*)d_in[5];
    const float* vg  = (const float*)d_in[6];
    const float* vb  = (const float*)d_in[7];
    const float* vm  = (const float*)d_in[8];
    const float* vvr = (const float*)d_in[9];
    const float* lw  = (const float*)d_in[10];
    const float* lb  = (const float*)d_in[11];
    float* out = (float*)d_out;

    float* ws   = (float*)d_ws;
    float* q_bn = ws;                        // [b][m][n][k]  2,097,152 f
    float* v_bn = ws + 2097152;              // [b][m][vd]    2,097,152 f
    float* k_bf = ws + 4194304;              // [b][k][m]       524,288 f
    float* clam = ws + 4718592;              // [b][k][vd]       32,768 f
    __bf16* wbf = (__bf16*)(ws + 4751360);   // 36,864 bf16 (18,432 f)
    float* s_bf = ws + 4769792;              // [b][m][52][4]  6,815,744 f
    const size_t ws_need = (size_t)(4769792 + 6815744) * sizeof(float);

    hipMemsetAsync(clam, 0, 32768 * sizeof(float), stream);
    hipLaunchKernelGGL(k_wbf, dim3(36), dim3(256), 0, stream, w, wbf);
    hipLaunchKernelGGL(k_qkv, dim3(512), dim3(256), 0, stream,
                       x, wbf, qg, qb, qm, qvr, vg, vb, vm, vvr, q_bn, k_bf, v_bn);
    hipLaunchKernelGGL(k_softmax, dim3(512), dim3(256), 0, stream, k_bf);
    hipLaunchKernelGGL(k_clam, dim3(256), dim3(256), 0, stream, k_bf, v_bn, clam);
    if (ws_size >= ws_need) {
        hipLaunchKernelGGL(k_sq, dim3(512), dim3(256), 0, stream, q_bn, lw, s_bf);
        hipLaunchKernelGGL(k_fuse, dim3(256), dim3(512), 0, stream,
                           v_bn, q_bn, clam, s_bf, lb, out);
    } else {
        hipLaunchKernelGGL(k_fuse_v, dim3(256), dim3(512), 0, stream,
                           v_bn, q_bn, clam, lw, lb, out);
    }
}

// Round 14
// 114.600 us; speedup vs baseline: 1.1652x; 1.1652x over previous
//
#include <hip/hip_runtime.h>
#include <hip/hip_bf16.h>

constexpr int B_ = 32, C_ = 256, H_ = 32, W_ = 32, M_ = 1024;
constexpr int NH = 4, DK = 16, DV = 64;
constexpr float EPS = 1e-5f;

using bf16x8 = __bf16 __attribute__((ext_vector_type(8)));
using f32x4  = float __attribute__((ext_vector_type(4)));

struct alignas(8) Bf4 { __bf16 a, b, c, d; };

// ---------------- Kernel 0: W fp32 -> bf16 (once; 36864 elems) -------------
__global__ __launch_bounds__(256) void k_wbf(
    const float* __restrict__ w, __bf16* __restrict__ wbf)
{
    int i = blockIdx.x * 256 + threadIdx.x;          // 9216 float4s
    if (i < 9216) {
        float4 f = reinterpret_cast<const float4*>(w)[i];
        Bf4 o{(__bf16)f.x, (__bf16)f.y, (__bf16)f.z, (__bf16)f.w};
        *reinterpret_cast<Bf4*>(&wbf[i * 4]) = o;
    }
}

// ---------------- Kernel 1: qkv = W @ x via bf16 MFMA, + BN ----------------
// (round-11 version, proven)
__global__ __launch_bounds__(256) void k_qkv(
    const float* __restrict__ x, const __bf16* __restrict__ wbf,
    const float* __restrict__ qg, const float* __restrict__ qb,
    const float* __restrict__ qm, const float* __restrict__ qv,
    const float* __restrict__ vg, const float* __restrict__ vb,
    const float* __restrict__ vm, const float* __restrict__ vv,
    float* __restrict__ q_out, float* __restrict__ k_out,
    float* __restrict__ v_out)
{
    __shared__ __bf16 xT[64 * 72];                 // 9 KB
    __shared__ __align__(16) float ostage[64 * 68]; // 17 KB (reused per pass)
    __shared__ __align__(16) float inv_s[144];
    __shared__ __align__(16) float add_s[144];

    const int b    = blockIdx.x >> 4;
    const int m0   = (blockIdx.x & 15) * 64;
    const int tid  = threadIdx.x;
    const int wv   = tid >> 6;
    const int lane = tid & 63;
    const int col  = lane & 15;
    const int rowg = lane >> 4;

    if (tid < 144) {
        float iv = 1.f, ad = 0.f;
        if (tid < 64)       { iv = qg[tid] * rsqrtf(qv[tid] + EPS); ad = qb[tid] - qm[tid] * iv; }
        else if (tid >= 80) { int d = tid - 80; iv = vg[d] * rsqrtf(vv[d] + EPS); ad = vb[d] - vm[d] * iv; }
        inv_s[tid] = iv; add_s[tid] = ad;
    }

    f32x4 acc[9];
#pragma unroll
    for (int j = 0; j < 9; j++) acc[j] = (f32x4){0.f, 0.f, 0.f, 0.f};

    for (int c0 = 0; c0 < C_; c0 += 64) {
        __syncthreads();
#pragma unroll
        for (int i = 0; i < 4; i++) {
            int flat = tid + 256 * i;
            int m = flat & 63, c4 = flat >> 6;
            const float* xp = &x[((size_t)b * C_ + c0 + c4 * 4) * M_ + m0 + m];
            float f0 = xp[0], f1 = xp[M_], f2 = xp[2 * M_], f3 = xp[3 * M_];
            Bf4 o{(__bf16)f0, (__bf16)f1, (__bf16)f2, (__bf16)f3};
            *reinterpret_cast<Bf4*>(&xT[m * 72 + c4 * 4]) = o;
        }
        __syncthreads();
#pragma unroll
        for (int ks = 0; ks < 2; ks++) {
            const int cl = ks * 32 + rowg * 8;
            bf16x8 bf = *reinterpret_cast<const bf16x8*>(
                &xT[(16 * wv + col) * 72 + cl]);
#pragma unroll
            for (int j = 0; j < 9; j++) {
                bf16x8 af = *reinterpret_cast<const bf16x8*>(
                    &wbf[(size_t)(16 * j + col) * C_ + c0 + cl]);
                acc[j] = __builtin_amdgcn_mfma_f32_16x16x32_bf16(af, bf, acc[j], 0, 0, 0);
            }
        }
    }

    const int mloc = 16 * wv + col;

    __syncthreads();
#pragma unroll
    for (int j = 0; j < 4; j++)
        *reinterpret_cast<f32x4*>(&ostage[mloc * 68 + 16 * j + rowg * 4]) = acc[j];
    __syncthreads();
#pragma unroll
    for (int i = 0; i < 4; i++) {
        int fl = tid + 256 * i;
        int m = fl >> 4, oc4 = (fl & 15) * 4;
        float4 vr = *reinterpret_cast<const float4*>(&ostage[m * 68 + oc4]);
        float4 iv = *reinterpret_cast<const float4*>(&inv_s[oc4]);
        float4 ad = *reinterpret_cast<const float4*>(&add_s[oc4]);
        float4 rs{vr.x * iv.x + ad.x, vr.y * iv.y + ad.y,
                  vr.z * iv.z + ad.z, vr.w * iv.w + ad.w};
        *reinterpret_cast<float4*>(&q_out[((size_t)b * M_ + m0 + m) * 64 + oc4]) = rs;
    }

    __syncthreads();
#pragma unroll
    for (int r = 0; r < 4; r++)
        ostage[(rowg * 4 + r) * 68 + mloc] = acc[4][r];
    __syncthreads();
    {
        int kk = tid >> 4, m4 = (tid & 15) * 4;
        float4 vr = *reinterpret_cast<const float4*>(&ostage[kk * 68 + m4]);
        *reinterpret_cast<float4*>(&k_out[((size_t)b * DK + kk) * M_ + m0 + m4]) = vr;
    }

    __syncthreads();
#pragma unroll
    for (int j = 5; j < 9; j++)
        *reinterpret_cast<f32x4*>(&ostage[mloc * 68 + 16 * (j - 5) + rowg * 4]) = acc[j];
    __syncthreads();
#pragma unroll
    for (int i = 0; i < 4; i++) {
        int fl = tid + 256 * i;
        int m = fl >> 4, oc4 = (fl & 15) * 4;
        float4 vr = *reinterpret_cast<const float4*>(&ostage[m * 68 + oc4]);
        float4 iv = *reinterpret_cast<const float4*>(&inv_s[80 + oc4]);
        float4 ad = *reinterpret_cast<const float4*>(&add_s[80 + oc4]);
        float4 rs{vr.x * iv.x + ad.x, vr.y * iv.y + ad.y,
                  vr.z * iv.z + ad.z, vr.w * iv.w + ad.w};
        *reinterpret_cast<float4*>(&v_out[((size_t)b * M_ + m0 + m) * 64 + oc4]) = rs;
    }
}

// ---------------- Kernel 2: softmax over M per (b,k) row, in place ---------
__global__ __launch_bounds__(256) void k_softmax(float* __restrict__ kl)
{
    float* p = kl + (size_t)blockIdx.x * M_;
    const int tid = threadIdx.x;
    float v[4];
    float mx = -1e30f;
#pragma unroll
    for (int i = 0; i < 4; i++) { v[i] = p[tid + 256 * i]; mx = fmaxf(mx, v[i]); }
#pragma unroll
    for (int off = 32; off >= 1; off >>= 1) mx = fmaxf(mx, __shfl_xor(mx, off));
    __shared__ float red[8];
    if ((tid & 63) == 0) red[tid >> 6] = mx;
    __syncthreads();
    mx = fmaxf(fmaxf(red[0], red[1]), fmaxf(red[2], red[3]));
    float s = 0.f;
#pragma unroll
    for (int i = 0; i < 4; i++) { v[i] = __expf(v[i] - mx); s += v[i]; }
#pragma unroll
    for (int off = 32; off >= 1; off >>= 1) s += __shfl_xor(s, off);
    if ((tid & 63) == 0) red[4 + (tid >> 6)] = s;
    __syncthreads();
    s = red[4] + red[5] + red[6] + red[7];
    float inv = 1.f / s;
#pragma unroll
    for (int i = 0; i < 4; i++) p[tid + 256 * i] = v[i] * inv;
}

// ---------------- Kernel 3: content_lam[b,k,vd] = sum_m ksm * v ------------
__global__ __launch_bounds__(256) void k_clam(
    const float* __restrict__ ksm, const float* __restrict__ vbn,
    float* __restrict__ clam)
{
    const int b   = blockIdx.x >> 3;
    const int m0  = (blockIdx.x & 7) * 128;
    const int tid = threadIdx.x;
    const int vd  = tid & 63;
    const int kq  = tid >> 6;
    float acc[4] = {0.f, 0.f, 0.f, 0.f};
    for (int mi = 0; mi < 128; mi++) {
        const int m = m0 + mi;
        const float vvv = vbn[(b * M_ + m) * DV + vd];
#pragma unroll
        for (int j = 0; j < 4; j++)
            acc[j] = fmaf(ksm[(b * DK + kq + 4 * j) * M_ + m], vvv, acc[j]);
    }
#pragma unroll
    for (int j = 0; j < 4; j++)
        atomicAdd(&clam[(b * DK + kq + 4 * j) * DV + vd], acc[j]);
}

// ---------------- Kernel 3.5 (REWRITTEN): s[b][m][52t][4n] = q . lw^T ------
// grid 32b x 16 (64-m tiles), 256 thr.  Stage q tile qs[64][68] (17 KB,
// padded; coalesced float4 loads) + lws[16*52] (taps 49..51 = 0).
// Output: 3328 float4 = 13/thread, i4 = tid + 256*r -> m=i4/52, t=i4%52.
// qs reads ~52-lane broadcast (conflict-free); lws stride-1; stores
// perfectly coalesced (consecutive i4 -> consecutive 16 B).
__global__ __launch_bounds__(256) void k_sq(
    const float* __restrict__ qbn, const float* __restrict__ lw,
    float* __restrict__ s)
{
    __shared__ float qs[64][68];           // 17.4 KB
    __shared__ float lws[16 * 52];         // 3.3 KB
    const int b   = blockIdx.x >> 4;
    const int m0  = (blockIdx.x & 15) * 64;
    const int tid = threadIdx.x;

    for (int i = tid; i < 832; i += 256) {
        int k = i / 52, t = i % 52;
        lws[i] = (t < 49) ? lw[k * 49 + t] : 0.f;
    }
#pragma unroll
    for (int i = 0; i < 4; i++) {          // 1024 float4s of q
        int f4 = tid + 256 * i;
        int m = f4 >> 4, c4 = (f4 & 15) * 4;
        *reinterpret_cast<float4*>(&qs[m][c4]) =
            *reinterpret_cast<const float4*>(
                &qbn[((size_t)b * M_ + m0 + m) * 64 + c4]);
    }
    __syncthreads();

#pragma unroll 1
    for (int r = 0; r < 13; r++) {
        const int i4 = tid + 256 * r;      // 0..3327
        const int m = i4 / 52, t = i4 % 52;
        float4 acc = make_float4(0.f, 0.f, 0.f, 0.f);
#pragma unroll
        for (int k = 0; k < 16; k++) {
            const float lwv = lws[k * 52 + t];
            acc.x = fmaf(qs[m][k],      lwv, acc.x);
            acc.y = fmaf(qs[m][16 + k], lwv, acc.y);
            acc.z = fmaf(qs[m][32 + k], lwv, acc.z);
            acc.w = fmaf(qs[m][48 + k], lwv, acc.w);
        }
        *reinterpret_cast<float4*>(
            &s[(((size_t)b * M_ + m0) * 52 + i4) * 4]) = acc;
    }
}

// ---------------- Kernel 4: out = q.(clam+lb) + sum_tap s*v ----------------
// (round-13 version, proven 49.5 us)
__global__ __launch_bounds__(512) void k_fuse(
    const float* __restrict__ vbn, const float* __restrict__ qbn,
    const float* __restrict__ clam, const float* __restrict__ s,
    const float* __restrict__ lb, float* __restrict__ out)
{
    __shared__ float v_s[10 * 32 * 64];    // 80 KB
    __shared__ float s_s[32 * 52 * 4];     // 26.6 KB
    __shared__ float ostage[64][132];      // 33.8 KB
    __shared__ float cl_s[16 * 64];
    __shared__ float lb_s[16];

    const int b   = blockIdx.x >> 3;
    const int rt  = blockIdx.x & 7;
    const int h0  = rt * 4;
    const int tid = threadIdx.x;

    for (int i4 = tid; i4 < 5120; i4 += 512) {   // v halo
        int r   = i4 >> 9;
        int rem = (i4 & 511) * 4;
        int gr  = h0 - 3 + r;
        float4 val = make_float4(0.f, 0.f, 0.f, 0.f);
        if (gr >= 0 && gr < H_)
            val = *reinterpret_cast<const float4*>(&vbn[(b * M_ + gr * W_) * DV + rem]);
        *reinterpret_cast<float4*>(&v_s[r * 2048 + rem]) = val;
    }
    if (tid < 256)
        *reinterpret_cast<float4*>(&cl_s[tid * 4]) =
            *reinterpret_cast<const float4*>(&clam[b * DK * DV + tid * 4]);
    if (tid < 16) lb_s[tid] = lb[tid];

    const int vd  = tid & 63;
    const int pg  = tid >> 6;
    const int px0 = pg * 4;

    for (int grp = 0; grp < 4; grp++) {
        const float* sg = s + ((size_t)b * M_ + (h0 + grp) * W_) * 208;
        for (int i4 = tid; i4 < 1664; i4 += 512)
            reinterpret_cast<float4*>(s_s)[i4] =
                reinterpret_cast<const float4*>(sg)[i4];
        __syncthreads();

        float po[4][4];
#pragma unroll
        for (int ip = 0; ip < 4; ip++)
#pragma unroll
            for (int n = 0; n < 4; n++) po[ip][n] = 0.f;

#pragma unroll 1
        for (int dy = 0; dy < 7; dy++) {
            const int rbase = (grp + dy) * W_;
            float vr[10];
#pragma unroll
            for (int j = 0; j < 10; j++) {
                const int colc = px0 - 3 + j;
                vr[j] = (colc >= 0 && colc < W_) ? v_s[(rbase + colc) * DV + vd] : 0.f;
            }
#pragma unroll
            for (int dx = 0; dx < 7; dx++) {
                const int tap = dy * 7 + dx;
#pragma unroll
                for (int ip = 0; ip < 4; ip++) {
                    float4 s4 = *reinterpret_cast<const float4*>(
                        &s_s[(px0 + ip) * 208 + tap * 4]);
                    const float vv = vr[ip + dx];
                    po[ip][0] = fmaf(vv, s4.x, po[ip][0]);
                    po[ip][1] = fmaf(vv, s4.y, po[ip][1]);
                    po[ip][2] = fmaf(vv, s4.z, po[ip][2]);
                    po[ip][3] = fmaf(vv, s4.w, po[ip][3]);
                }
            }
        }
        const int mrow = (h0 + grp) * W_;
#pragma unroll
        for (int ip = 0; ip < 4; ip++) {
            const int p = px0 + ip;
            const int m = mrow + p;
            float lamv[16];
#pragma unroll
            for (int k = 0; k < 16; k++)
                lamv[k] = cl_s[k * DV + vd] + lb_s[k];
            const float* qp = qbn + (size_t)(b * M_ + m) * NH * DK;
            float4 ov;
            float* ovp = reinterpret_cast<float*>(&ov);
#pragma unroll
            for (int n = 0; n < 4; n++) {
                const float4* q4 = reinterpret_cast<const float4*>(qp + n * DK);
                float4 qa = q4[0], qb4 = q4[1], qc = q4[2], qd = q4[3];
                ovp[n] = po[ip][n]
                       + qa.x * lamv[0] + qa.y * lamv[1] + qa.z * lamv[2] + qa.w * lamv[3]
                       + qb4.x * lamv[4] + qb4.y * lamv[5] + qb4.z * lamv[6] + qb4.w * lamv[7]
                       + qc.x * lamv[8] + qc.y * lamv[9] + qc.z * lamv[10] + qc.w * lamv[11]
                       + qd.x * lamv[12] + qd.y * lamv[13] + qd.z * lamv[14] + qd.w * lamv[15];
            }
            *reinterpret_cast<float4*>(&ostage[vd][p * 4]) = ov;
        }
        __syncthreads();
        {
            const int mrow4 = mrow * 4;
            for (int i4 = tid; i4 < 2048; i4 += 512) {
                const int vdw  = i4 >> 5;
                const int off4 = (i4 & 31) * 4;
                float4 val = *reinterpret_cast<const float4*>(&ostage[vdw][off4]);
                *reinterpret_cast<float4*>(
                    out + (size_t)b * (C_ * M_) + (size_t)vdw * 4096 + mrow4 + off4) = val;
            }
        }
        __syncthreads();
    }
}

// ---------------- Fallback kernel 4 (round-12 proven, 65 us) ---------------
__global__ __launch_bounds__(512) void k_fuse_v(
    const float* __restrict__ vbn, const float* __restrict__ qbn,
    const float* __restrict__ clam,
    const float* __restrict__ lw, const float* __restrict__ lb,
    float* __restrict__ out)
{
    __shared__ float v_s[10 * 32 * 64];
    __shared__ float ostage[64][260];
    __shared__ float lw_t[49 * 16];
    __shared__ float cl_s[16 * 64];
    __shared__ float lb_s[16];

    const int b   = blockIdx.x >> 3;
    const int rt  = blockIdx.x & 7;
    const int h0  = rt * 4;
    const int tid = threadIdx.x;

    for (int i4 = tid; i4 < 5120; i4 += 512) {
        int r   = i4 >> 9;
        int rem = (i4 & 511) * 4;
        int gr  = h0 - 3 + r;
        float4 val = make_float4(0.f, 0.f, 0.f, 0.f);
        if (gr >= 0 && gr < H_)
            val = *reinterpret_cast<const float4*>(&vbn[(b * M_ + gr * W_) * DV + rem]);
        *reinterpret_cast<float4*>(&v_s[r * 2048 + rem]) = val;
    }
    for (int i = tid; i < 784; i += 512) {
        int tap = i >> 4, k = i & 15;
        lw_t[i] = lw[k * 49 + tap];
    }
    if (tid < 256)
        *reinterpret_cast<float4*>(&cl_s[tid * 4]) =
            *reinterpret_cast<const float4*>(&clam[b * DK * DV + tid * 4]);
    if (tid < 16) lb_s[tid] = lb[tid];
    __syncthreads();

    const int vd  = tid & 63;
    const int pg  = tid >> 6;
    const int px0 = pg * 4;

    for (int grp = 0; grp < 4; grp++) {
        float plam[4][16];
#pragma unroll
        for (int ip = 0; ip < 4; ip++)
#pragma unroll
            for (int k = 0; k < 16; k++) plam[ip][k] = 0.f;

#pragma unroll 1
        for (int dy = 0; dy < 7; dy++) {
            const int rbase = (grp + dy) * W_;
            float vr[10];
#pragma unroll
            for (int j = 0; j < 10; j++) {
                const int col = px0 - 3 + j;
                vr[j] = (col >= 0 && col < W_) ? v_s[(rbase + col) * DV + vd] : 0.f;
            }
#pragma unroll
            for (int dx = 0; dx < 7; dx++) {
                const float* lwp = &lw_t[(dy * 7 + dx) * 16];
                float4 l0 = *reinterpret_cast<const float4*>(lwp);
                float4 l1 = *reinterpret_cast<const float4*>(lwp + 4);
                float4 l2 = *reinterpret_cast<const float4*>(lwp + 8);
                float4 l3 = *reinterpret_cast<const float4*>(lwp + 12);
                const float lwv[16] = {l0.x, l0.y, l0.z, l0.w, l1.x, l1.y, l1.z, l1.w,
                                       l2.x, l2.y, l2.z, l2.w, l3.x, l3.y, l3.z, l3.w};
#pragma unroll
                for (int ip = 0; ip < 4; ip++) {
                    const float vvv = vr[ip + dx];
#pragma unroll
                    for (int k = 0; k < 16; k++)
                        plam[ip][k] = fmaf(vvv, lwv[k], plam[ip][k]);
                }
            }
        }
#pragma unroll
        for (int ip = 0; ip < 4; ip++) {
            const int p = grp * 32 + px0 + ip;
            const int m = h0 * W_ + p;
            float lamv[16];
#pragma unroll
            for (int k = 0; k < 16; k++)
                lamv[k] = plam[ip][k] + cl_s[k * DV + vd] + lb_s[k];
            const float* qp = qbn + (size_t)(b * M_ + m) * NH * DK;
            float4 ov;
            float* ovp = reinterpret_cast<float*>(&ov);
#pragma unroll
            for (int n = 0; n < 4; n++) {
                const float4* q4 = reinterpret_cast<const float4*>(qp + n * DK);
                float4 qa = q4[0], qb4 = q4[1], qc = q4[2], qd = q4[3];
                ovp[n] = qa.x * lamv[0] + qa.y * lamv[1] + qa.z * lamv[2] + qa.w * lamv[3]
                       + qb4.x * lamv[4] + qb4.y * lamv[5] + qb4.z * lamv[6] + qb4.w * lamv[7]
                       + qc.x * lamv[8] + qc.y * lamv[9] + qc.z * lamv[10] + qc.w * lamv[11]
                       + qd.x * lamv[12] + qd.y * lamv[13] + qd.z * lamv[14] + qd.w * lamv[15];
            }
            *reinterpret_cast<float4*>(&ostage[vd][(p & 63) * 4]) = ov;
        }
        if (grp & 1) {
            __syncthreads();
            const int half = grp >> 1;
            const int mb4 = (h0 + half * 2) * W_ * 4;
            for (int i = tid; i < 4096; i += 512) {
                const int vdw  = i >> 6;
                const int off4 = (i & 63) * 4;
                float4 val = *reinterpret_cast<const float4*>(&ostage[vdw][off4]);
                *reinterpret_cast<float4*>(
                    out + (size_t)b * (C_ * M_) + (size_t)vdw * 4096 + mb4 + off4) = val;
            }
            __syncthreads();
        }
    }
}

extern "C" void kernel_launch(void* const* d_in, const int* in_sizes, int n_in,
                              void* d_out, int out_size, void* d_ws, size_t ws_size,
                              hipStream_t stream)
{
    (void)in_sizes; (void)n_in; (void)out_size;
    const float* x   = (const float*)d_in[0];
    const float* w   = (const float*)d_in[1];
    const float* qg  = (const float*)d_in[2];
    const float* qb  = (const float*)d_in[3];
    const float* qm  = (const float*)d_in[4];
    const float* qvr = (const float*)d_in[5];
    const float* vg  = (const float*)d_in[6];
    const float* vb  = (const float*)d_in[7];
    const float* vm  = (const float*)d_in[8];
    const float* vvr = (const float*)d_in[9];
    const float* lw  = (const float*)d_in[10];
    const float* lb  = (const float*)d_in[11];
    float* out = (float*)d_out;

    float* ws   = (float*)d_ws;
    float* q_bn = ws;                        // [b][m][n][k]  2,097,152 f
    float* v_bn = ws + 2097152;              // [b][m][vd]    2,097,152 f
    float* k_bf = ws + 4194304;              // [b][k][m]       524,288 f
    float* clam = ws + 4718592;              // [b][k][vd]       32,768 f
    __bf16* wbf = (__bf16*)(ws + 4751360);   // 36,864 bf16 (18,432 f)
    float* s_bf = ws + 4769792;              // [b][m][52][4]  6,815,744 f
    const size_t ws_need = (size_t)(4769792 + 6815744) * sizeof(float);

    hipMemsetAsync(clam, 0, 32768 * sizeof(float), stream);
    hipLaunchKernelGGL(k_wbf, dim3(36), dim3(256), 0, stream, w, wbf);
    hipLaunchKernelGGL(k_qkv, dim3(512), dim3(256), 0, stream,
                       x, wbf, qg, qb, qm, qvr, vg, vb, vm, vvr, q_bn, k_bf, v_bn);
    hipLaunchKernelGGL(k_softmax, dim3(512), dim3(256), 0, stream, k_bf);
    hipLaunchKernelGGL(k_clam, dim3(256), dim3(256), 0, stream, k_bf, v_bn, clam);
    if (ws_size >= ws_need) {
        hipLaunchKernelGGL(k_sq, dim3(512), dim3(256), 0, stream, q_bn, lw, s_bf);
        hipLaunchKernelGGL(k_fuse, dim3(256), dim3(512), 0, stream,
                           v_bn, q_bn, clam, s_bf, lb, out);
    } else {
        hipLaunchKernelGGL(k_fuse_v, dim3(256), dim3(512), 0, stream,
                           v_bn, q_bn, clam, lw, lb, out);
    }
}

// Round 15
// 98.946 us; speedup vs baseline: 1.3495x; 1.1582x over previous
//
#include <hip/hip_runtime.h>
#include <hip/hip_bf16.h>

constexpr int B_ = 32, C_ = 256, H_ = 32, W_ = 32, M_ = 1024;
constexpr int NH = 4, DK = 16, DV = 64;
constexpr float EPS = 1e-5f;

using bf16x8 = __bf16 __attribute__((ext_vector_type(8)));
using f32x4  = float __attribute__((ext_vector_type(4)));

struct alignas(8) Bf4 { __bf16 a, b, c, d; };

// ---------------- Kernel 0: W fp32 -> bf16 (once; 36864 elems) -------------
__global__ __launch_bounds__(256) void k_wbf(
    const float* __restrict__ w, __bf16* __restrict__ wbf)
{
    int i = blockIdx.x * 256 + threadIdx.x;          // 9216 float4s
    if (i < 9216) {
        float4 f = reinterpret_cast<const float4*>(w)[i];
        Bf4 o{(__bf16)f.x, (__bf16)f.y, (__bf16)f.z, (__bf16)f.w};
        *reinterpret_cast<Bf4*>(&wbf[i * 4]) = o;
    }
}

// ---------------- Kernel 1: qkv = W @ x via bf16 MFMA, + BN ----------------
// (round-11 version, proven)
__global__ __launch_bounds__(256) void k_qkv(
    const float* __restrict__ x, const __bf16* __restrict__ wbf,
    const float* __restrict__ qg, const float* __restrict__ qb,
    const float* __restrict__ qm, const float* __restrict__ qv,
    const float* __restrict__ vg, const float* __restrict__ vb,
    const float* __restrict__ vm, const float* __restrict__ vv,
    float* __restrict__ q_out, float* __restrict__ k_out,
    float* __restrict__ v_out)
{
    __shared__ __bf16 xT[64 * 72];                 // 9 KB
    __shared__ __align__(16) float ostage[64 * 68]; // 17 KB (reused per pass)
    __shared__ __align__(16) float inv_s[144];
    __shared__ __align__(16) float add_s[144];

    const int b    = blockIdx.x >> 4;
    const int m0   = (blockIdx.x & 15) * 64;
    const int tid  = threadIdx.x;
    const int wv   = tid >> 6;
    const int lane = tid & 63;
    const int col  = lane & 15;
    const int rowg = lane >> 4;

    if (tid < 144) {
        float iv = 1.f, ad = 0.f;
        if (tid < 64)       { iv = qg[tid] * rsqrtf(qv[tid] + EPS); ad = qb[tid] - qm[tid] * iv; }
        else if (tid >= 80) { int d = tid - 80; iv = vg[d] * rsqrtf(vv[d] + EPS); ad = vb[d] - vm[d] * iv; }
        inv_s[tid] = iv; add_s[tid] = ad;
    }

    f32x4 acc[9];
#pragma unroll
    for (int j = 0; j < 9; j++) acc[j] = (f32x4){0.f, 0.f, 0.f, 0.f};

    for (int c0 = 0; c0 < C_; c0 += 64) {
        __syncthreads();
#pragma unroll
        for (int i = 0; i < 4; i++) {
            int flat = tid + 256 * i;
            int m = flat & 63, c4 = flat >> 6;
            const float* xp = &x[((size_t)b * C_ + c0 + c4 * 4) * M_ + m0 + m];
            float f0 = xp[0], f1 = xp[M_], f2 = xp[2 * M_], f3 = xp[3 * M_];
            Bf4 o{(__bf16)f0, (__bf16)f1, (__bf16)f2, (__bf16)f3};
            *reinterpret_cast<Bf4*>(&xT[m * 72 + c4 * 4]) = o;
        }
        __syncthreads();
#pragma unroll
        for (int ks = 0; ks < 2; ks++) {
            const int cl = ks * 32 + rowg * 8;
            bf16x8 bf = *reinterpret_cast<const bf16x8*>(
                &xT[(16 * wv + col) * 72 + cl]);
#pragma unroll
            for (int j = 0; j < 9; j++) {
                bf16x8 af = *reinterpret_cast<const bf16x8*>(
                    &wbf[(size_t)(16 * j + col) * C_ + c0 + cl]);
                acc[j] = __builtin_amdgcn_mfma_f32_16x16x32_bf16(af, bf, acc[j], 0, 0, 0);
            }
        }
    }

    const int mloc = 16 * wv + col;

    __syncthreads();
#pragma unroll
    for (int j = 0; j < 4; j++)
        *reinterpret_cast<f32x4*>(&ostage[mloc * 68 + 16 * j + rowg * 4]) = acc[j];
    __syncthreads();
#pragma unroll
    for (int i = 0; i < 4; i++) {
        int fl = tid + 256 * i;
        int m = fl >> 4, oc4 = (fl & 15) * 4;
        float4 vr = *reinterpret_cast<const float4*>(&ostage[m * 68 + oc4]);
        float4 iv = *reinterpret_cast<const float4*>(&inv_s[oc4]);
        float4 ad = *reinterpret_cast<const float4*>(&add_s[oc4]);
        float4 rs{vr.x * iv.x + ad.x, vr.y * iv.y + ad.y,
                  vr.z * iv.z + ad.z, vr.w * iv.w + ad.w};
        *reinterpret_cast<float4*>(&q_out[((size_t)b * M_ + m0 + m) * 64 + oc4]) = rs;
    }

    __syncthreads();
#pragma unroll
    for (int r = 0; r < 4; r++)
        ostage[(rowg * 4 + r) * 68 + mloc] = acc[4][r];
    __syncthreads();
    {
        int kk = tid >> 4, m4 = (tid & 15) * 4;
        float4 vr = *reinterpret_cast<const float4*>(&ostage[kk * 68 + m4]);
        *reinterpret_cast<float4*>(&k_out[((size_t)b * DK + kk) * M_ + m0 + m4]) = vr;
    }

    __syncthreads();
#pragma unroll
    for (int j = 5; j < 9; j++)
        *reinterpret_cast<f32x4*>(&ostage[mloc * 68 + 16 * (j - 5) + rowg * 4]) = acc[j];
    __syncthreads();
#pragma unroll
    for (int i = 0; i < 4; i++) {
        int fl = tid + 256 * i;
        int m = fl >> 4, oc4 = (fl & 15) * 4;
        float4 vr = *reinterpret_cast<const float4*>(&ostage[m * 68 + oc4]);
        float4 iv = *reinterpret_cast<const float4*>(&inv_s[80 + oc4]);
        float4 ad = *reinterpret_cast<const float4*>(&add_s[80 + oc4]);
        float4 rs{vr.x * iv.x + ad.x, vr.y * iv.y + ad.y,
                  vr.z * iv.z + ad.z, vr.w * iv.w + ad.w};
        *reinterpret_cast<float4*>(&v_out[((size_t)b * M_ + m0 + m) * 64 + oc4]) = rs;
    }
}

// ---------------- Kernel 2: softmax over M per (b,k) row, in place ---------
__global__ __launch_bounds__(256) void k_softmax(float* __restrict__ kl)
{
    float* p = kl + (size_t)blockIdx.x * M_;
    const int tid = threadIdx.x;
    float v[4];
    float mx = -1e30f;
#pragma unroll
    for (int i = 0; i < 4; i++) { v[i] = p[tid + 256 * i]; mx = fmaxf(mx, v[i]); }
#pragma unroll
    for (int off = 32; off >= 1; off >>= 1) mx = fmaxf(mx, __shfl_xor(mx, off));
    __shared__ float red[8];
    if ((tid & 63) == 0) red[tid >> 6] = mx;
    __syncthreads();
    mx = fmaxf(fmaxf(red[0], red[1]), fmaxf(red[2], red[3]));
    float s = 0.f;
#pragma unroll
    for (int i = 0; i < 4; i++) { v[i] = __expf(v[i] - mx); s += v[i]; }
#pragma unroll
    for (int off = 32; off >= 1; off >>= 1) s += __shfl_xor(s, off);
    if ((tid & 63) == 0) red[4 + (tid >> 6)] = s;
    __syncthreads();
    s = red[4] + red[5] + red[6] + red[7];
    float inv = 1.f / s;
#pragma unroll
    for (int i = 0; i < 4; i++) p[tid + 256 * i] = v[i] * inv;
}

// ---------------- Kernel 3: content_lam[b,k,vd] = sum_m ksm * v ------------
__global__ __launch_bounds__(256) void k_clam(
    const float* __restrict__ ksm, const float* __restrict__ vbn,
    float* __restrict__ clam)
{
    const int b   = blockIdx.x >> 3;
    const int m0  = (blockIdx.x & 7) * 128;
    const int tid = threadIdx.x;
    const int vd  = tid & 63;
    const int kq  = tid >> 6;
    float acc[4] = {0.f, 0.f, 0.f, 0.f};
    for (int mi = 0; mi < 128; mi++) {
        const int m = m0 + mi;
        const float vvv = vbn[(b * M_ + m) * DV + vd];
#pragma unroll
        for (int j = 0; j < 4; j++)
            acc[j] = fmaf(ksm[(b * DK + kq + 4 * j) * M_ + m], vvv, acc[j]);
    }
#pragma unroll
    for (int j = 0; j < 4; j++)
        atomicAdd(&clam[(b * DK + kq + 4 * j) * DV + vd], acc[j]);
}

// ---------------- Kernel 4: fully fused: s-compute + pos + content ---------
// grid 32b x 16 row-pairs, 512 thr.  Per output row (grp):
//  1) stage qs[32][68] (this row's q, coalesced; reused by s-compute+epilogue)
//  2) compute s_s[32px][52tap][4n] in LDS (416 thr: m=tid/13, t4=(tid%13)*4;
//     256 FMA + 80 LDS reads each) -- replaces the k_sq kernel + 54 MB of
//     s traffic entirely.
//  3) dy-loop: v DIRECT from global into vr[10] (unroll 1, no hoisting --
//     r8 lesson); po[4][4] += vr * s4 (broadcast b128).  v_s LDS deleted:
//     halo staging never amortized (80 KB staged = 72 KB consumed).
//  4) epilogue: content (q from qs LDS) + po -> ostage -> coalesced flush.
// LDS ~74.8 KB -> 2 blocks/CU (grid 512 = exactly 2/CU) = 4 waves/SIMD.
__global__ __launch_bounds__(512) void k_fuse(
    const float* __restrict__ vbn, const float* __restrict__ qbn,
    const float* __restrict__ clam, const float* __restrict__ lw,
    const float* __restrict__ lb, float* __restrict__ out)
{
    __shared__ float qs[32][68];           // 8.7 KB
    __shared__ float lws[16 * 52];         // 3.3 KB (taps 49..51 = 0)
    __shared__ float s_s[32 * 208];        // 26.6 KB  [px][tap*4+n]
    __shared__ float ostage[64][132];      // 33.8 KB
    __shared__ float cl_s[16 * 64];        // 4 KB
    __shared__ float lb_s[16];

    const int b   = blockIdx.x >> 4;
    const int rt  = blockIdx.x & 15;
    const int h0  = rt * 2;
    const int tid = threadIdx.x;

    for (int i = tid; i < 832; i += 512) {
        int k = i / 52, t = i % 52;
        lws[i] = (t < 49) ? lw[k * 49 + t] : 0.f;
    }
    if (tid < 256)
        *reinterpret_cast<float4*>(&cl_s[tid * 4]) =
            *reinterpret_cast<const float4*>(&clam[b * DK * DV + tid * 4]);
    if (tid < 16) lb_s[tid] = lb[tid];

    const int vd  = tid & 63;
    const int pg  = tid >> 6;
    const int px0 = pg * 4;
    const float* vb_b = vbn + (size_t)b * M_ * DV + vd;

    for (int grp = 0; grp < 2; grp++) {
        const int mrow = (h0 + grp) * W_;
        // 1) stage q row tile (512 float4, coalesced)
        {
            const int m = tid >> 4, c4 = (tid & 15) * 4;
            *reinterpret_cast<float4*>(&qs[m][c4]) =
                *reinterpret_cast<const float4*>(
                    &qbn[((size_t)b * M_ + mrow + m) * 64 + c4]);
        }
        __syncthreads();               // qs (and lws/cl_s on iter 0) ready

        // 2) s_s[m][t][n] = sum_k qs[m][n*16+k] * lws[k][t]
        if (tid < 416) {
            const int m  = tid / 13;
            const int t4 = (tid % 13) * 4;
            f32x4 a0 = {0.f,0.f,0.f,0.f}, a1 = a0, a2 = a0, a3 = a0;
#pragma unroll
            for (int k = 0; k < 16; k++) {
                float4 lw4 = *reinterpret_cast<const float4*>(&lws[k * 52 + t4]);
                float q0 = qs[m][k],      q1 = qs[m][16 + k];
                float q2 = qs[m][32 + k], q3 = qs[m][48 + k];
                a0[0] = fmaf(q0, lw4.x, a0[0]); a0[1] = fmaf(q1, lw4.x, a0[1]);
                a0[2] = fmaf(q2, lw4.x, a0[2]); a0[3] = fmaf(q3, lw4.x, a0[3]);
                a1[0] = fmaf(q0, lw4.y, a1[0]); a1[1] = fmaf(q1, lw4.y, a1[1]);
                a1[2] = fmaf(q2, lw4.y, a1[2]); a1[3] = fmaf(q3, lw4.y, a1[3]);
                a2[0] = fmaf(q0, lw4.z, a2[0]); a2[1] = fmaf(q1, lw4.z, a2[1]);
                a2[2] = fmaf(q2, lw4.z, a2[2]); a2[3] = fmaf(q3, lw4.z, a2[3]);
                a3[0] = fmaf(q0, lw4.w, a3[0]); a3[1] = fmaf(q1, lw4.w, a3[1]);
                a3[2] = fmaf(q2, lw4.w, a3[2]); a3[3] = fmaf(q3, lw4.w, a3[3]);
            }
            float* sp = &s_s[m * 208 + t4 * 4];
            *reinterpret_cast<f32x4*>(sp)      = a0;
            *reinterpret_cast<f32x4*>(sp + 4)  = a1;
            *reinterpret_cast<f32x4*>(sp + 8)  = a2;
            *reinterpret_cast<f32x4*>(sp + 12) = a3;
        }
        __syncthreads();               // s_s ready

        // 3) position path: v direct from global
        float po[4][4];
#pragma unroll
        for (int ip = 0; ip < 4; ip++)
#pragma unroll
            for (int n = 0; n < 4; n++) po[ip][n] = 0.f;

#pragma unroll 1
        for (int dy = 0; dy < 7; dy++) {
            const int gr = h0 + grp - 3 + dy;     // block-uniform
            float vr[10];
            if (gr >= 0 && gr < H_) {
#pragma unroll
                for (int j = 0; j < 10; j++) {
                    const int colc = px0 - 3 + j; // wave-uniform validity
                    vr[j] = (colc >= 0 && colc < W_)
                          ? vb_b[(size_t)(gr * W_ + colc) * DV] : 0.f;
                }
            } else {
#pragma unroll
                for (int j = 0; j < 10; j++) vr[j] = 0.f;
            }
#pragma unroll
            for (int dx = 0; dx < 7; dx++) {
                const int tap = dy * 7 + dx;
#pragma unroll
                for (int ip = 0; ip < 4; ip++) {
                    float4 s4 = *reinterpret_cast<const float4*>(
                        &s_s[(px0 + ip) * 208 + tap * 4]);
                    const float vv = vr[ip + dx];
                    po[ip][0] = fmaf(vv, s4.x, po[ip][0]);
                    po[ip][1] = fmaf(vv, s4.y, po[ip][1]);
                    po[ip][2] = fmaf(vv, s4.z, po[ip][2]);
                    po[ip][3] = fmaf(vv, s4.w, po[ip][3]);
                }
            }
        }

        // 4) epilogue: content (q from LDS) + po -> ostage
#pragma unroll
        for (int ip = 0; ip < 4; ip++) {
            const int p = px0 + ip;
            float lamv[16];
#pragma unroll
            for (int k = 0; k < 16; k++)
                lamv[k] = cl_s[k * DV + vd] + lb_s[k];
            float4 ov;
            float* ovp = reinterpret_cast<float*>(&ov);
#pragma unroll
            for (int n = 0; n < 4; n++) {
                const float4* q4 = reinterpret_cast<const float4*>(&qs[p][n * 16]);
                float4 qa = q4[0], qb4 = q4[1], qc = q4[2], qd = q4[3];
                ovp[n] = po[ip][n]
                       + qa.x * lamv[0] + qa.y * lamv[1] + qa.z * lamv[2] + qa.w * lamv[3]
                       + qb4.x * lamv[4] + qb4.y * lamv[5] + qb4.z * lamv[6] + qb4.w * lamv[7]
                       + qc.x * lamv[8] + qc.y * lamv[9] + qc.z * lamv[10] + qc.w * lamv[11]
                       + qd.x * lamv[12] + qd.y * lamv[13] + qd.z * lamv[14] + qd.w * lamv[15];
            }
            *reinterpret_cast<float4*>(&ostage[vd][p * 4]) = ov;
        }
        __syncthreads();
        // flush this row: 2048 float4, lanes consecutive -> coalesced
        {
            const int mrow4 = mrow * 4;
            for (int i4 = tid; i4 < 2048; i4 += 512) {
                const int vdw  = i4 >> 5;
                const int off4 = (i4 & 31) * 4;
                float4 val = *reinterpret_cast<const float4*>(&ostage[vdw][off4]);
                *reinterpret_cast<float4*>(
                    out + (size_t)b * (C_ * M_) + (size_t)vdw * 4096 + mrow4 + off4) = val;
            }
        }
        __syncthreads();
    }
}

extern "C" void kernel_launch(void* const* d_in, const int* in_sizes, int n_in,
                              void* d_out, int out_size, void* d_ws, size_t ws_size,
                              hipStream_t stream)
{
    (void)in_sizes; (void)n_in; (void)out_size; (void)ws_size;
    const float* x   = (const float*)d_in[0];
    const float* w   = (const float*)d_in[1];
    const float* qg  = (const float*)d_in[2];
    const float* qb  = (const float*)d_in[3];
    const float* qm  = (const float*)d_in[4];
    const float* qvr = (const float*)d_in[5];
    const float* vg  = (const float*)d_in[6];
    const float* vb  = (const float*)d_in[7];
    const float* vm  = (const float*)d_in[8];
    const float* vvr = (const float*)d_in[9];
    const float* lw  = (const float*)d_in[10];
    const float* lb  = (const float*)d_in[11];
    float* out = (float*)d_out;

    float* ws   = (float*)d_ws;
    float* q_bn = ws;                        // [b][m][n][k]  2,097,152 f
    float* v_bn = ws + 2097152;              // [b][m][vd]    2,097,152 f
    float* k_bf = ws + 4194304;              // [b][k][m]       524,288 f
    float* clam = ws + 4718592;              // [b][k][vd]       32,768 f
    __bf16* wbf = (__bf16*)(ws + 4751360);   // 36,864 bf16

    hipMemsetAsync(clam, 0, 32768 * sizeof(float), stream);
    hipLaunchKernelGGL(k_wbf, dim3(36), dim3(256), 0, stream, w, wbf);
    hipLaunchKernelGGL(k_qkv, dim3(512), dim3(256), 0, stream,
                       x, wbf, qg, qb, qm, qvr, vg, vb, vm, vvr, q_bn, k_bf, v_bn);
    hipLaunchKernelGGL(k_softmax, dim3(512), dim3(256), 0, stream, k_bf);
    hipLaunchKernelGGL(k_clam, dim3(256), dim3(256), 0, stream, k_bf, v_bn, clam);
    hipLaunchKernelGGL(k_fuse, dim3(512), dim3(512), 0, stream,
                       v_bn, q_bn, clam, lw, lb, out);
}

// Round 16
// 95.834 us; speedup vs baseline: 1.3934x; 1.0325x over previous
//
#include <hip/hip_runtime.h>
#include <hip/hip_bf16.h>

constexpr int B_ = 32, C_ = 256, H_ = 32, W_ = 32, M_ = 1024;
constexpr int NH = 4, DK = 16, DV = 64;
constexpr float EPS = 1e-5f;

using bf16x8 = __bf16 __attribute__((ext_vector_type(8)));
using f32x4  = float __attribute__((ext_vector_type(4)));

struct alignas(8) Bf4 { __bf16 a, b, c, d; };

// ---------------- Kernel 0: W fp32 -> bf16 (once; 36864 elems) -------------
__global__ __launch_bounds__(256) void k_wbf(
    const float* __restrict__ w, __bf16* __restrict__ wbf)
{
    int i = blockIdx.x * 256 + threadIdx.x;          // 9216 float4s
    if (i < 9216) {
        float4 f = reinterpret_cast<const float4*>(w)[i];
        Bf4 o{(__bf16)f.x, (__bf16)f.y, (__bf16)f.z, (__bf16)f.w};
        *reinterpret_cast<Bf4*>(&wbf[i * 4]) = o;
    }
}

// ---------------- Kernel 1: qkv = W @ x via bf16 MFMA, + BN ----------------
// (round-11 version, proven)
__global__ __launch_bounds__(256) void k_qkv(
    const float* __restrict__ x, const __bf16* __restrict__ wbf,
    const float* __restrict__ qg, const float* __restrict__ qb,
    const float* __restrict__ qm, const float* __restrict__ qv,
    const float* __restrict__ vg, const float* __restrict__ vb,
    const float* __restrict__ vm, const float* __restrict__ vv,
    float* __restrict__ q_out, float* __restrict__ k_out,
    float* __restrict__ v_out)
{
    __shared__ __bf16 xT[64 * 72];                 // 9 KB
    __shared__ __align__(16) float ostage[64 * 68]; // 17 KB (reused per pass)
    __shared__ __align__(16) float inv_s[144];
    __shared__ __align__(16) float add_s[144];

    const int b    = blockIdx.x >> 4;
    const int m0   = (blockIdx.x & 15) * 64;
    const int tid  = threadIdx.x;
    const int wv   = tid >> 6;
    const int lane = tid & 63;
    const int col  = lane & 15;
    const int rowg = lane >> 4;

    if (tid < 144) {
        float iv = 1.f, ad = 0.f;
        if (tid < 64)       { iv = qg[tid] * rsqrtf(qv[tid] + EPS); ad = qb[tid] - qm[tid] * iv; }
        else if (tid >= 80) { int d = tid - 80; iv = vg[d] * rsqrtf(vv[d] + EPS); ad = vb[d] - vm[d] * iv; }
        inv_s[tid] = iv; add_s[tid] = ad;
    }

    f32x4 acc[9];
#pragma unroll
    for (int j = 0; j < 9; j++) acc[j] = (f32x4){0.f, 0.f, 0.f, 0.f};

    for (int c0 = 0; c0 < C_; c0 += 64) {
        __syncthreads();
#pragma unroll
        for (int i = 0; i < 4; i++) {
            int flat = tid + 256 * i;
            int m = flat & 63, c4 = flat >> 6;
            const float* xp = &x[((size_t)b * C_ + c0 + c4 * 4) * M_ + m0 + m];
            float f0 = xp[0], f1 = xp[M_], f2 = xp[2 * M_], f3 = xp[3 * M_];
            Bf4 o{(__bf16)f0, (__bf16)f1, (__bf16)f2, (__bf16)f3};
            *reinterpret_cast<Bf4*>(&xT[m * 72 + c4 * 4]) = o;
        }
        __syncthreads();
#pragma unroll
        for (int ks = 0; ks < 2; ks++) {
            const int cl = ks * 32 + rowg * 8;
            bf16x8 bf = *reinterpret_cast<const bf16x8*>(
                &xT[(16 * wv + col) * 72 + cl]);
#pragma unroll
            for (int j = 0; j < 9; j++) {
                bf16x8 af = *reinterpret_cast<const bf16x8*>(
                    &wbf[(size_t)(16 * j + col) * C_ + c0 + cl]);
                acc[j] = __builtin_amdgcn_mfma_f32_16x16x32_bf16(af, bf, acc[j], 0, 0, 0);
            }
        }
    }

    const int mloc = 16 * wv + col;

    __syncthreads();
#pragma unroll
    for (int j = 0; j < 4; j++)
        *reinterpret_cast<f32x4*>(&ostage[mloc * 68 + 16 * j + rowg * 4]) = acc[j];
    __syncthreads();
#pragma unroll
    for (int i = 0; i < 4; i++) {
        int fl = tid + 256 * i;
        int m = fl >> 4, oc4 = (fl & 15) * 4;
        float4 vr = *reinterpret_cast<const float4*>(&ostage[m * 68 + oc4]);
        float4 iv = *reinterpret_cast<const float4*>(&inv_s[oc4]);
        float4 ad = *reinterpret_cast<const float4*>(&add_s[oc4]);
        float4 rs{vr.x * iv.x + ad.x, vr.y * iv.y + ad.y,
                  vr.z * iv.z + ad.z, vr.w * iv.w + ad.w};
        *reinterpret_cast<float4*>(&q_out[((size_t)b * M_ + m0 + m) * 64 + oc4]) = rs;
    }

    __syncthreads();
#pragma unroll
    for (int r = 0; r < 4; r++)
        ostage[(rowg * 4 + r) * 68 + mloc] = acc[4][r];
    __syncthreads();
    {
        int kk = tid >> 4, m4 = (tid & 15) * 4;
        float4 vr = *reinterpret_cast<const float4*>(&ostage[kk * 68 + m4]);
        *reinterpret_cast<float4*>(&k_out[((size_t)b * DK + kk) * M_ + m0 + m4]) = vr;
    }

    __syncthreads();
#pragma unroll
    for (int j = 5; j < 9; j++)
        *reinterpret_cast<f32x4*>(&ostage[mloc * 68 + 16 * (j - 5) + rowg * 4]) = acc[j];
    __syncthreads();
#pragma unroll
    for (int i = 0; i < 4; i++) {
        int fl = tid + 256 * i;
        int m = fl >> 4, oc4 = (fl & 15) * 4;
        float4 vr = *reinterpret_cast<const float4*>(&ostage[m * 68 + oc4]);
        float4 iv = *reinterpret_cast<const float4*>(&inv_s[80 + oc4]);
        float4 ad = *reinterpret_cast<const float4*>(&add_s[80 + oc4]);
        float4 rs{vr.x * iv.x + ad.x, vr.y * iv.y + ad.y,
                  vr.z * iv.z + ad.z, vr.w * iv.w + ad.w};
        *reinterpret_cast<float4*>(&v_out[((size_t)b * M_ + m0 + m) * 64 + oc4]) = rs;
    }
}

// ---------------- Kernel 2: softmax over M per (b,k) row, in place ---------
__global__ __launch_bounds__(256) void k_softmax(float* __restrict__ kl)
{
    float* p = kl + (size_t)blockIdx.x * M_;
    const int tid = threadIdx.x;
    float v[4];
    float mx = -1e30f;
#pragma unroll
    for (int i = 0; i < 4; i++) { v[i] = p[tid + 256 * i]; mx = fmaxf(mx, v[i]); }
#pragma unroll
    for (int off = 32; off >= 1; off >>= 1) mx = fmaxf(mx, __shfl_xor(mx, off));
    __shared__ float red[8];
    if ((tid & 63) == 0) red[tid >> 6] = mx;
    __syncthreads();
    mx = fmaxf(fmaxf(red[0], red[1]), fmaxf(red[2], red[3]));
    float s = 0.f;
#pragma unroll
    for (int i = 0; i < 4; i++) { v[i] = __expf(v[i] - mx); s += v[i]; }
#pragma unroll
    for (int off = 32; off >= 1; off >>= 1) s += __shfl_xor(s, off);
    if ((tid & 63) == 0) red[4 + (tid >> 6)] = s;
    __syncthreads();
    s = red[4] + red[5] + red[6] + red[7];
    float inv = 1.f / s;
#pragma unroll
    for (int i = 0; i < 4; i++) p[tid + 256 * i] = v[i] * inv;
}

// ---------------- Kernel 3: content_lam[b,k,vd] = sum_m ksm * v ------------
__global__ __launch_bounds__(256) void k_clam(
    const float* __restrict__ ksm, const float* __restrict__ vbn,
    float* __restrict__ clam)
{
    const int b   = blockIdx.x >> 3;
    const int m0  = (blockIdx.x & 7) * 128;
    const int tid = threadIdx.x;
    const int vd  = tid & 63;
    const int kq  = tid >> 6;
    float acc[4] = {0.f, 0.f, 0.f, 0.f};
    for (int mi = 0; mi < 128; mi++) {
        const int m = m0 + mi;
        const float vvv = vbn[(b * M_ + m) * DV + vd];
#pragma unroll
        for (int j = 0; j < 4; j++)
            acc[j] = fmaf(ksm[(b * DK + kq + 4 * j) * M_ + m], vvv, acc[j]);
    }
#pragma unroll
    for (int j = 0; j < 4; j++)
        atomicAdd(&clam[(b * DK + kq + 4 * j) * DV + vd], acc[j]);
}

// ---------------- Kernel 4: fused s-compute + pos + content (r15 base) ----
// r16 deltas: (a) v-load double-buffer pipeline (vrC/vrN) -- dy+1 loads
// issue before dy's FMAs, covering ~300cy L2 latency with 224cy of issue;
// (b) lamv (cl+lb) hoisted out of ip loop (ip-invariant);
// (c) next-grp q prefetched into regs during pos phase.
__global__ __launch_bounds__(512) void k_fuse(
    const float* __restrict__ vbn, const float* __restrict__ qbn,
    const float* __restrict__ clam, const float* __restrict__ lw,
    const float* __restrict__ lb, float* __restrict__ out)
{
    __shared__ float qs[32][68];           // 8.7 KB
    __shared__ float lws[16 * 52];         // 3.3 KB (taps 49..51 = 0)
    __shared__ float s_s[32 * 208];        // 26.6 KB  [px][tap*4+n]
    __shared__ float ostage[64][132];      // 33.8 KB
    __shared__ float cl_s[16 * 64];        // 4 KB
    __shared__ float lb_s[16];

    const int b   = blockIdx.x >> 4;
    const int rt  = blockIdx.x & 15;
    const int h0  = rt * 2;
    const int tid = threadIdx.x;

    for (int i = tid; i < 832; i += 512) {
        int k = i / 52, t = i % 52;
        lws[i] = (t < 49) ? lw[k * 49 + t] : 0.f;
    }
    if (tid < 256)
        *reinterpret_cast<float4*>(&cl_s[tid * 4]) =
            *reinterpret_cast<const float4*>(&clam[b * DK * DV + tid * 4]);
    if (tid < 16) lb_s[tid] = lb[tid];

    const int vd  = tid & 63;
    const int pg  = tid >> 6;
    const int px0 = pg * 4;
    const float* vb_b = vbn + (size_t)b * M_ * DV + vd;

    const int qm_ = tid >> 4, qc4 = (tid & 15) * 4;   // q staging coords
    float4 qreg = *reinterpret_cast<const float4*>(
        &qbn[((size_t)b * M_ + h0 * W_ + qm_) * 64 + qc4]);

    for (int grp = 0; grp < 2; grp++) {
        const int mrow = (h0 + grp) * W_;
        // 1) write prefetched q row tile
        *reinterpret_cast<float4*>(&qs[qm_][qc4]) = qreg;
        __syncthreads();               // qs (and lws/cl_s on iter 0) ready

        // 2) s_s[m][t][n] = sum_k qs[m][n*16+k] * lws[k][t]
        if (tid < 416) {
            const int m  = tid / 13;
            const int t4 = (tid % 13) * 4;
            f32x4 a0 = {0.f,0.f,0.f,0.f}, a1 = a0, a2 = a0, a3 = a0;
#pragma unroll
            for (int k = 0; k < 16; k++) {
                float4 lw4 = *reinterpret_cast<const float4*>(&lws[k * 52 + t4]);
                float q0 = qs[m][k],      q1 = qs[m][16 + k];
                float q2 = qs[m][32 + k], q3 = qs[m][48 + k];
                a0[0] = fmaf(q0, lw4.x, a0[0]); a0[1] = fmaf(q1, lw4.x, a0[1]);
                a0[2] = fmaf(q2, lw4.x, a0[2]); a0[3] = fmaf(q3, lw4.x, a0[3]);
                a1[0] = fmaf(q0, lw4.y, a1[0]); a1[1] = fmaf(q1, lw4.y, a1[1]);
                a1[2] = fmaf(q2, lw4.y, a1[2]); a1[3] = fmaf(q3, lw4.y, a1[3]);
                a2[0] = fmaf(q0, lw4.z, a2[0]); a2[1] = fmaf(q1, lw4.z, a2[1]);
                a2[2] = fmaf(q2, lw4.z, a2[2]); a2[3] = fmaf(q3, lw4.z, a2[3]);
                a3[0] = fmaf(q0, lw4.w, a3[0]); a3[1] = fmaf(q1, lw4.w, a3[1]);
                a3[2] = fmaf(q2, lw4.w, a3[2]); a3[3] = fmaf(q3, lw4.w, a3[3]);
            }
            float* sp = &s_s[m * 208 + t4 * 4];
            *reinterpret_cast<f32x4*>(sp)      = a0;
            *reinterpret_cast<f32x4*>(sp + 4)  = a1;
            *reinterpret_cast<f32x4*>(sp + 8)  = a2;
            *reinterpret_cast<f32x4*>(sp + 12) = a3;
        }
        __syncthreads();               // s_s ready

        // (c) prefetch next grp's q while pos path runs
        if (grp == 0)
            qreg = *reinterpret_cast<const float4*>(
                &qbn[((size_t)b * M_ + (h0 + 1) * W_ + qm_) * 64 + qc4]);

        // 3) position path: v direct from global, double-buffered (vrC/vrN)
        float po[4][4];
#pragma unroll
        for (int ip = 0; ip < 4; ip++)
#pragma unroll
            for (int n = 0; n < 4; n++) po[ip][n] = 0.f;

        float vrC[10], vrN[10];
        {
            const int gr = h0 + grp - 3;           // dy = 0 row
            if (gr >= 0 && gr < H_) {
#pragma unroll
                for (int j = 0; j < 10; j++) {
                    const int colc = px0 - 3 + j;
                    vrC[j] = (colc >= 0 && colc < W_)
                           ? vb_b[(size_t)(gr * W_ + colc) * DV] : 0.f;
                }
            } else {
#pragma unroll
                for (int j = 0; j < 10; j++) vrC[j] = 0.f;
            }
        }
#pragma unroll 1
        for (int dy = 0; dy < 7; dy++) {
            // issue next row's loads first (covered by this row's FMAs)
            const int grn = h0 + grp - 2 + dy;     // dy+1 row
            if (dy < 6 && grn >= 0 && grn < H_) {
#pragma unroll
                for (int j = 0; j < 10; j++) {
                    const int colc = px0 - 3 + j;
                    vrN[j] = (colc >= 0 && colc < W_)
                           ? vb_b[(size_t)(grn * W_ + colc) * DV] : 0.f;
                }
            } else {
#pragma unroll
                for (int j = 0; j < 10; j++) vrN[j] = 0.f;
            }
#pragma unroll
            for (int dx = 0; dx < 7; dx++) {
                const int tap = dy * 7 + dx;
#pragma unroll
                for (int ip = 0; ip < 4; ip++) {
                    float4 s4 = *reinterpret_cast<const float4*>(
                        &s_s[(px0 + ip) * 208 + tap * 4]);
                    const float vv = vrC[ip + dx];
                    po[ip][0] = fmaf(vv, s4.x, po[ip][0]);
                    po[ip][1] = fmaf(vv, s4.y, po[ip][1]);
                    po[ip][2] = fmaf(vv, s4.z, po[ip][2]);
                    po[ip][3] = fmaf(vv, s4.w, po[ip][3]);
                }
            }
#pragma unroll
            for (int j = 0; j < 10; j++) vrC[j] = vrN[j];
        }

        // 4) epilogue: lamv hoisted (ip-invariant), content q from LDS
        float lamv[16];
#pragma unroll
        for (int k = 0; k < 16; k++)
            lamv[k] = cl_s[k * DV + vd] + lb_s[k];
#pragma unroll
        for (int ip = 0; ip < 4; ip++) {
            const int p = px0 + ip;
            float4 ov;
            float* ovp = reinterpret_cast<float*>(&ov);
#pragma unroll
            for (int n = 0; n < 4; n++) {
                const float4* q4 = reinterpret_cast<const float4*>(&qs[p][n * 16]);
                float4 qa = q4[0], qb4 = q4[1], qc = q4[2], qd = q4[3];
                ovp[n] = po[ip][n]
                       + qa.x * lamv[0] + qa.y * lamv[1] + qa.z * lamv[2] + qa.w * lamv[3]
                       + qb4.x * lamv[4] + qb4.y * lamv[5] + qb4.z * lamv[6] + qb4.w * lamv[7]
                       + qc.x * lamv[8] + qc.y * lamv[9] + qc.z * lamv[10] + qc.w * lamv[11]
                       + qd.x * lamv[12] + qd.y * lamv[13] + qd.z * lamv[14] + qd.w * lamv[15];
            }
            *reinterpret_cast<float4*>(&ostage[vd][p * 4]) = ov;
        }
        __syncthreads();
        // flush this row: 2048 float4, lanes consecutive -> coalesced
        {
            const int mrow4 = mrow * 4;
            for (int i4 = tid; i4 < 2048; i4 += 512) {
                const int vdw  = i4 >> 5;
                const int off4 = (i4 & 31) * 4;
                float4 val = *reinterpret_cast<const float4*>(&ostage[vdw][off4]);
                *reinterpret_cast<float4*>(
                    out + (size_t)b * (C_ * M_) + (size_t)vdw * 4096 + mrow4 + off4) = val;
            }
        }
        __syncthreads();
    }
}

extern "C" void kernel_launch(void* const* d_in, const int* in_sizes, int n_in,
                              void* d_out, int out_size, void* d_ws, size_t ws_size,
                              hipStream_t stream)
{
    (void)in_sizes; (void)n_in; (void)out_size; (void)ws_size;
    const float* x   = (const float*)d_in[0];
    const float* w   = (const float*)d_in[1];
    const float* qg  = (const float*)d_in[2];
    const float* qb  = (const float*)d_in[3];
    const float* qm  = (const float*)d_in[4];
    const float* qvr = (const float*)d_in[5];
    const float* vg  = (const float*)d_in[6];
    const float* vb  = (const float*)d_in[7];
    const float* vm  = (const float*)d_in[8];
    const float* vvr = (const float*)d_in[9];
    const float* lw  = (const float*)d_in[10];
    const float* lb  = (const float*)d_in[11];
    float* out = (float*)d_out;

    float* ws   = (float*)d_ws;
    float* q_bn = ws;                        // [b][m][n][k]  2,097,152 f
    float* v_bn = ws + 2097152;              // [b][m][vd]    2,097,152 f
    float* k_bf = ws + 4194304;              // [b][k][m]       524,288 f
    float* clam = ws + 4718592;              // [b][k][vd]       32,768 f
    __bf16* wbf = (__bf16*)(ws + 4751360);   // 36,864 bf16

    hipMemsetAsync(clam, 0, 32768 * sizeof(float), stream);
    hipLaunchKernelGGL(k_wbf, dim3(36), dim3(256), 0, stream, w, wbf);
    hipLaunchKernelGGL(k_qkv, dim3(512), dim3(256), 0, stream,
                       x, wbf, qg, qb, qm, qvr, vg, vb, vm, vvr, q_bn, k_bf, v_bn);
    hipLaunchKernelGGL(k_softmax, dim3(512), dim3(256), 0, stream, k_bf);
    hipLaunchKernelGGL(k_clam, dim3(256), dim3(256), 0, stream, k_bf, v_bn, clam);
    hipLaunchKernelGGL(k_fuse, dim3(512), dim3(512), 0, stream,
                       v_bn, q_bn, clam, lw, lb, out);
}

// Round 17
// 91.872 us; speedup vs baseline: 1.4534x; 1.0431x over previous
//
#include <hip/hip_runtime.h>
#include <hip/hip_bf16.h>

constexpr int B_ = 32, C_ = 256, H_ = 32, W_ = 32, M_ = 1024;
constexpr int NH = 4, DK = 16, DV = 64;
constexpr float EPS = 1e-5f;

using bf16x8 = __bf16 __attribute__((ext_vector_type(8)));
using f32x4  = float __attribute__((ext_vector_type(4)));

struct alignas(8) Bf4 { __bf16 a, b, c, d; };

// ---------------- Kernel 0: W fp32 -> bf16 (once; 36864 elems) -------------
__global__ __launch_bounds__(256) void k_wbf(
    const float* __restrict__ w, __bf16* __restrict__ wbf)
{
    int i = blockIdx.x * 256 + threadIdx.x;          // 9216 float4s
    if (i < 9216) {
        float4 f = reinterpret_cast<const float4*>(w)[i];
        Bf4 o{(__bf16)f.x, (__bf16)f.y, (__bf16)f.z, (__bf16)f.w};
        *reinterpret_cast<Bf4*>(&wbf[i * 4]) = o;
    }
}

// ---------------- Kernel 1: qkv = W @ x via bf16 MFMA, + BN ----------------
// (round-11 version, proven)
__global__ __launch_bounds__(256) void k_qkv(
    const float* __restrict__ x, const __bf16* __restrict__ wbf,
    const float* __restrict__ qg, const float* __restrict__ qb,
    const float* __restrict__ qm, const float* __restrict__ qv,
    const float* __restrict__ vg, const float* __restrict__ vb,
    const float* __restrict__ vm, const float* __restrict__ vv,
    float* __restrict__ q_out, float* __restrict__ k_out,
    float* __restrict__ v_out)
{
    __shared__ __bf16 xT[64 * 72];                 // 9 KB
    __shared__ __align__(16) float ostage[64 * 68]; // 17 KB (reused per pass)
    __shared__ __align__(16) float inv_s[144];
    __shared__ __align__(16) float add_s[144];

    const int b    = blockIdx.x >> 4;
    const int m0   = (blockIdx.x & 15) * 64;
    const int tid  = threadIdx.x;
    const int wv   = tid >> 6;
    const int lane = tid & 63;
    const int col  = lane & 15;
    const int rowg = lane >> 4;

    if (tid < 144) {
        float iv = 1.f, ad = 0.f;
        if (tid < 64)       { iv = qg[tid] * rsqrtf(qv[tid] + EPS); ad = qb[tid] - qm[tid] * iv; }
        else if (tid >= 80) { int d = tid - 80; iv = vg[d] * rsqrtf(vv[d] + EPS); ad = vb[d] - vm[d] * iv; }
        inv_s[tid] = iv; add_s[tid] = ad;
    }

    f32x4 acc[9];
#pragma unroll
    for (int j = 0; j < 9; j++) acc[j] = (f32x4){0.f, 0.f, 0.f, 0.f};

    for (int c0 = 0; c0 < C_; c0 += 64) {
        __syncthreads();
#pragma unroll
        for (int i = 0; i < 4; i++) {
            int flat = tid + 256 * i;
            int m = flat & 63, c4 = flat >> 6;
            const float* xp = &x[((size_t)b * C_ + c0 + c4 * 4) * M_ + m0 + m];
            float f0 = xp[0], f1 = xp[M_], f2 = xp[2 * M_], f3 = xp[3 * M_];
            Bf4 o{(__bf16)f0, (__bf16)f1, (__bf16)f2, (__bf16)f3};
            *reinterpret_cast<Bf4*>(&xT[m * 72 + c4 * 4]) = o;
        }
        __syncthreads();
#pragma unroll
        for (int ks = 0; ks < 2; ks++) {
            const int cl = ks * 32 + rowg * 8;
            bf16x8 bf = *reinterpret_cast<const bf16x8*>(
                &xT[(16 * wv + col) * 72 + cl]);
#pragma unroll
            for (int j = 0; j < 9; j++) {
                bf16x8 af = *reinterpret_cast<const bf16x8*>(
                    &wbf[(size_t)(16 * j + col) * C_ + c0 + cl]);
                acc[j] = __builtin_amdgcn_mfma_f32_16x16x32_bf16(af, bf, acc[j], 0, 0, 0);
            }
        }
    }

    const int mloc = 16 * wv + col;

    __syncthreads();
#pragma unroll
    for (int j = 0; j < 4; j++)
        *reinterpret_cast<f32x4*>(&ostage[mloc * 68 + 16 * j + rowg * 4]) = acc[j];
    __syncthreads();
#pragma unroll
    for (int i = 0; i < 4; i++) {
        int fl = tid + 256 * i;
        int m = fl >> 4, oc4 = (fl & 15) * 4;
        float4 vr = *reinterpret_cast<const float4*>(&ostage[m * 68 + oc4]);
        float4 iv = *reinterpret_cast<const float4*>(&inv_s[oc4]);
        float4 ad = *reinterpret_cast<const float4*>(&add_s[oc4]);
        float4 rs{vr.x * iv.x + ad.x, vr.y * iv.y + ad.y,
                  vr.z * iv.z + ad.z, vr.w * iv.w + ad.w};
        *reinterpret_cast<float4*>(&q_out[((size_t)b * M_ + m0 + m) * 64 + oc4]) = rs;
    }

    __syncthreads();
#pragma unroll
    for (int r = 0; r < 4; r++)
        ostage[(rowg * 4 + r) * 68 + mloc] = acc[4][r];
    __syncthreads();
    {
        int kk = tid >> 4, m4 = (tid & 15) * 4;
        float4 vr = *reinterpret_cast<const float4*>(&ostage[kk * 68 + m4]);
        *reinterpret_cast<float4*>(&k_out[((size_t)b * DK + kk) * M_ + m0 + m4]) = vr;
    }

    __syncthreads();
#pragma unroll
    for (int j = 5; j < 9; j++)
        *reinterpret_cast<f32x4*>(&ostage[mloc * 68 + 16 * (j - 5) + rowg * 4]) = acc[j];
    __syncthreads();
#pragma unroll
    for (int i = 0; i < 4; i++) {
        int fl = tid + 256 * i;
        int m = fl >> 4, oc4 = (fl & 15) * 4;
        float4 vr = *reinterpret_cast<const float4*>(&ostage[m * 68 + oc4]);
        float4 iv = *reinterpret_cast<const float4*>(&inv_s[80 + oc4]);
        float4 ad = *reinterpret_cast<const float4*>(&add_s[80 + oc4]);
        float4 rs{vr.x * iv.x + ad.x, vr.y * iv.y + ad.y,
                  vr.z * iv.z + ad.z, vr.w * iv.w + ad.w};
        *reinterpret_cast<float4*>(&v_out[((size_t)b * M_ + m0 + m) * 64 + oc4]) = rs;
    }
}

// ---------------- Kernel 2: softmax over M per (b,k) row, in place ---------
// r17: float4 I/O (m = 4*tid) -- 4x fewer VMEM instructions each way.
__global__ __launch_bounds__(256) void k_softmax(float* __restrict__ kl)
{
    float4* p4 = reinterpret_cast<float4*>(kl + (size_t)blockIdx.x * M_);
    const int tid = threadIdx.x;
    float4 v = p4[tid];
    float mx = fmaxf(fmaxf(v.x, v.y), fmaxf(v.z, v.w));
#pragma unroll
    for (int off = 32; off >= 1; off >>= 1) mx = fmaxf(mx, __shfl_xor(mx, off));
    __shared__ float red[8];
    if ((tid & 63) == 0) red[tid >> 6] = mx;
    __syncthreads();
    mx = fmaxf(fmaxf(red[0], red[1]), fmaxf(red[2], red[3]));
    v.x = __expf(v.x - mx); v.y = __expf(v.y - mx);
    v.z = __expf(v.z - mx); v.w = __expf(v.w - mx);
    float s = v.x + v.y + v.z + v.w;
#pragma unroll
    for (int off = 32; off >= 1; off >>= 1) s += __shfl_xor(s, off);
    if ((tid & 63) == 0) red[4 + (tid >> 6)] = s;
    __syncthreads();
    s = red[4] + red[5] + red[6] + red[7];
    float inv = 1.f / s;
    v.x *= inv; v.y *= inv; v.z *= inv; v.w *= inv;
    p4[tid] = v;
}

// ---------------- Kernel 3: content_lam[b,k,vd] = sum_m ksm * v ------------
// r17: grid 512 (m-chunks of 64) -- serial loop halved, 2 blocks/CU.
__global__ __launch_bounds__(256) void k_clam(
    const float* __restrict__ ksm, const float* __restrict__ vbn,
    float* __restrict__ clam)
{
    const int b   = blockIdx.x >> 4;
    const int m0  = (blockIdx.x & 15) * 64;
    const int tid = threadIdx.x;
    const int vd  = tid & 63;
    const int kq  = tid >> 6;
    float acc[4] = {0.f, 0.f, 0.f, 0.f};
    for (int mi = 0; mi < 64; mi++) {
        const int m = m0 + mi;
        const float vvv = vbn[(b * M_ + m) * DV + vd];
#pragma unroll
        for (int j = 0; j < 4; j++)
            acc[j] = fmaf(ksm[(b * DK + kq + 4 * j) * M_ + m], vvv, acc[j]);
    }
#pragma unroll
    for (int j = 0; j < 4; j++)
        atomicAdd(&clam[(b * DK + kq + 4 * j) * DV + vd], acc[j]);
}

// ---------------- Kernel 4: fused s-compute + pos + content ----------------
// (round-16 version, byte-identical: proven 48.4 us)
__global__ __launch_bounds__(512) void k_fuse(
    const float* __restrict__ vbn, const float* __restrict__ qbn,
    const float* __restrict__ clam, const float* __restrict__ lw,
    const float* __restrict__ lb, float* __restrict__ out)
{
    __shared__ float qs[32][68];           // 8.7 KB
    __shared__ float lws[16 * 52];         // 3.3 KB (taps 49..51 = 0)
    __shared__ float s_s[32 * 208];        // 26.6 KB  [px][tap*4+n]
    __shared__ float ostage[64][132];      // 33.8 KB
    __shared__ float cl_s[16 * 64];        // 4 KB
    __shared__ float lb_s[16];

    const int b   = blockIdx.x >> 4;
    const int rt  = blockIdx.x & 15;
    const int h0  = rt * 2;
    const int tid = threadIdx.x;

    for (int i = tid; i < 832; i += 512) {
        int k = i / 52, t = i % 52;
        lws[i] = (t < 49) ? lw[k * 49 + t] : 0.f;
    }
    if (tid < 256)
        *reinterpret_cast<float4*>(&cl_s[tid * 4]) =
            *reinterpret_cast<const float4*>(&clam[b * DK * DV + tid * 4]);
    if (tid < 16) lb_s[tid] = lb[tid];

    const int vd  = tid & 63;
    const int pg  = tid >> 6;
    const int px0 = pg * 4;
    const float* vb_b = vbn + (size_t)b * M_ * DV + vd;

    const int qm_ = tid >> 4, qc4 = (tid & 15) * 4;   // q staging coords
    float4 qreg = *reinterpret_cast<const float4*>(
        &qbn[((size_t)b * M_ + h0 * W_ + qm_) * 64 + qc4]);

    for (int grp = 0; grp < 2; grp++) {
        const int mrow = (h0 + grp) * W_;
        // 1) write prefetched q row tile
        *reinterpret_cast<float4*>(&qs[qm_][qc4]) = qreg;
        __syncthreads();               // qs (and lws/cl_s on iter 0) ready

        // 2) s_s[m][t][n] = sum_k qs[m][n*16+k] * lws[k][t]
        if (tid < 416) {
            const int m  = tid / 13;
            const int t4 = (tid % 13) * 4;
            f32x4 a0 = {0.f,0.f,0.f,0.f}, a1 = a0, a2 = a0, a3 = a0;
#pragma unroll
            for (int k = 0; k < 16; k++) {
                float4 lw4 = *reinterpret_cast<const float4*>(&lws[k * 52 + t4]);
                float q0 = qs[m][k],      q1 = qs[m][16 + k];
                float q2 = qs[m][32 + k], q3 = qs[m][48 + k];
                a0[0] = fmaf(q0, lw4.x, a0[0]); a0[1] = fmaf(q1, lw4.x, a0[1]);
                a0[2] = fmaf(q2, lw4.x, a0[2]); a0[3] = fmaf(q3, lw4.x, a0[3]);
                a1[0] = fmaf(q0, lw4.y, a1[0]); a1[1] = fmaf(q1, lw4.y, a1[1]);
                a1[2] = fmaf(q2, lw4.y, a1[2]); a1[3] = fmaf(q3, lw4.y, a1[3]);
                a2[0] = fmaf(q0, lw4.z, a2[0]); a2[1] = fmaf(q1, lw4.z, a2[1]);
                a2[2] = fmaf(q2, lw4.z, a2[2]); a2[3] = fmaf(q3, lw4.z, a2[3]);
                a3[0] = fmaf(q0, lw4.w, a3[0]); a3[1] = fmaf(q1, lw4.w, a3[1]);
                a3[2] = fmaf(q2, lw4.w, a3[2]); a3[3] = fmaf(q3, lw4.w, a3[3]);
            }
            float* sp = &s_s[m * 208 + t4 * 4];
            *reinterpret_cast<f32x4*>(sp)      = a0;
            *reinterpret_cast<f32x4*>(sp + 4)  = a1;
            *reinterpret_cast<f32x4*>(sp + 8)  = a2;
            *reinterpret_cast<f32x4*>(sp + 12) = a3;
        }
        __syncthreads();               // s_s ready

        // (c) prefetch next grp's q while pos path runs
        if (grp == 0)
            qreg = *reinterpret_cast<const float4*>(
                &qbn[((size_t)b * M_ + (h0 + 1) * W_ + qm_) * 64 + qc4]);

        // 3) position path: v direct from global, double-buffered (vrC/vrN)
        float po[4][4];
#pragma unroll
        for (int ip = 0; ip < 4; ip++)
#pragma unroll
            for (int n = 0; n < 4; n++) po[ip][n] = 0.f;

        float vrC[10], vrN[10];
        {
            const int gr = h0 + grp - 3;           // dy = 0 row
            if (gr >= 0 && gr < H_) {
#pragma unroll
                for (int j = 0; j < 10; j++) {
                    const int colc = px0 - 3 + j;
                    vrC[j] = (colc >= 0 && colc < W_)
                           ? vb_b[(size_t)(gr * W_ + colc) * DV] : 0.f;
                }
            } else {
#pragma unroll
                for (int j = 0; j < 10; j++) vrC[j] = 0.f;
            }
        }
#pragma unroll 1
        for (int dy = 0; dy < 7; dy++) {
            // issue next row's loads first (covered by this row's FMAs)
            const int grn = h0 + grp - 2 + dy;     // dy+1 row
            if (dy < 6 && grn >= 0 && grn < H_) {
#pragma unroll
                for (int j = 0; j < 10; j++) {
                    const int colc = px0 - 3 + j;
                    vrN[j] = (colc >= 0 && colc < W_)
                           ? vb_b[(size_t)(grn * W_ + colc) * DV] : 0.f;
                }
            } else {
#pragma unroll
                for (int j = 0; j < 10; j++) vrN[j] = 0.f;
            }
#pragma unroll
            for (int dx = 0; dx < 7; dx++) {
                const int tap = dy * 7 + dx;
#pragma unroll
                for (int ip = 0; ip < 4; ip++) {
                    float4 s4 = *reinterpret_cast<const float4*>(
                        &s_s[(px0 + ip) * 208 + tap * 4]);
                    const float vv = vrC[ip + dx];
                    po[ip][0] = fmaf(vv, s4.x, po[ip][0]);
                    po[ip][1] = fmaf(vv, s4.y, po[ip][1]);
                    po[ip][2] = fmaf(vv, s4.z, po[ip][2]);
                    po[ip][3] = fmaf(vv, s4.w, po[ip][3]);
                }
            }
#pragma unroll
            for (int j = 0; j < 10; j++) vrC[j] = vrN[j];
        }

        // 4) epilogue: lamv hoisted (ip-invariant), content q from LDS
        float lamv[16];
#pragma unroll
        for (int k = 0; k < 16; k++)
            lamv[k] = cl_s[k * DV + vd] + lb_s[k];
#pragma unroll
        for (int ip = 0; ip < 4; ip++) {
            const int p = px0 + ip;
            float4 ov;
            float* ovp = reinterpret_cast<float*>(&ov);
#pragma unroll
            for (int n = 0; n < 4; n++) {
                const float4* q4 = reinterpret_cast<const float4*>(&qs[p][n * 16]);
                float4 qa = q4[0], qb4 = q4[1], qc = q4[2], qd = q4[3];
                ovp[n] = po[ip][n]
                       + qa.x * lamv[0] + qa.y * lamv[1] + qa.z * lamv[2] + qa.w * lamv[3]
                       + qb4.x * lamv[4] + qb4.y * lamv[5] + qb4.z * lamv[6] + qb4.w * lamv[7]
                       + qc.x * lamv[8] + qc.y * lamv[9] + qc.z * lamv[10] + qc.w * lamv[11]
                       + qd.x * lamv[12] + qd.y * lamv[13] + qd.z * lamv[14] + qd.w * lamv[15];
            }
            *reinterpret_cast<float4*>(&ostage[vd][p * 4]) = ov;
        }
        __syncthreads();
        // flush this row: 2048 float4, lanes consecutive -> coalesced
        {
            const int mrow4 = mrow * 4;
            for (int i4 = tid; i4 < 2048; i4 += 512) {
                const int vdw  = i4 >> 5;
                const int off4 = (i4 & 31) * 4;
                float4 val = *reinterpret_cast<const float4*>(&ostage[vdw][off4]);
                *reinterpret_cast<float4*>(
                    out + (size_t)b * (C_ * M_) + (size_t)vdw * 4096 + mrow4 + off4) = val;
            }
        }
        __syncthreads();
    }
}

extern "C" void kernel_launch(void* const* d_in, const int* in_sizes, int n_in,
                              void* d_out, int out_size, void* d_ws, size_t ws_size,
                              hipStream_t stream)
{
    (void)in_sizes; (void)n_in; (void)out_size; (void)ws_size;
    const float* x   = (const float*)d_in[0];
    const float* w   = (const float*)d_in[1];
    const float* qg  = (const float*)d_in[2];
    const float* qb  = (const float*)d_in[3];
    const float* qm  = (const float*)d_in[4];
    const float* qvr = (const float*)d_in[5];
    const float* vg  = (const float*)d_in[6];
    const float* vb  = (const float*)d_in[7];
    const float* vm  = (const float*)d_in[8];
    const float* vvr = (const float*)d_in[9];
    const float* lw  = (const float*)d_in[10];
    const float* lb  = (const float*)d_in[11];
    float* out = (float*)d_out;

    float* ws   = (float*)d_ws;
    float* q_bn = ws;                        // [b][m][n][k]  2,097,152 f
    float* v_bn = ws + 2097152;              // [b][m][vd]    2,097,152 f
    float* k_bf = ws + 4194304;              // [b][k][m]       524,288 f
    float* clam = ws + 4718592;              // [b][k][vd]       32,768 f
    __bf16* wbf = (__bf16*)(ws + 4751360);   // 36,864 bf16

    hipMemsetAsync(clam, 0, 32768 * sizeof(float), stream);
    hipLaunchKernelGGL(k_wbf, dim3(36), dim3(256), 0, stream, w, wbf);
    hipLaunchKernelGGL(k_qkv, dim3(512), dim3(256), 0, stream,
                       x, wbf, qg, qb, qm, qvr, vg, vb, vm, vvr, q_bn, k_bf, v_bn);
    hipLaunchKernelGGL(k_softmax, dim3(512), dim3(256), 0, stream, k_bf);
    hipLaunchKernelGGL(k_clam, dim3(512), dim3(256), 0, stream, k_bf, v_bn, clam);
    hipLaunchKernelGGL(k_fuse, dim3(512), dim3(512), 0, stream,
                       v_bn, q_bn, clam, lw, lb, out);
}